// Round 11
// baseline (782.524 us; speedup 1.0000x reference)
//
#include <hip/hip_runtime.h>
#include <hip/hip_bf16.h>

#define H 64
#define PADW 88    // bf16 plane stride (shorts)
#define PADU 136   // bf16 plane stride K=128 (shorts)
#define PADT 68    // f32 transpose-buffer stride (floats)

typedef __attribute__((ext_vector_type(8))) short short8;
typedef __attribute__((ext_vector_type(4))) short short4v;
typedef __attribute__((ext_vector_type(4))) float floatx4;

#define MFMA(a, b, c) __builtin_amdgcn_mfma_f32_16x16x32_bf16(a, b, c, 0, 0, 0)

__device__ __forceinline__ float bf2f(short s) {
  union { unsigned int u; float f; } v;
  v.u = ((unsigned int)(unsigned short)s) << 16;
  return v.f;
}
__device__ __forceinline__ short f2bf(float f) {
  union { float f; unsigned int u; } v; v.f = f;
  unsigned int r = v.u + 0x7fffu + ((v.u >> 16) & 1u);  // RNE
  return (short)(r >> 16);
}
__device__ __forceinline__ void split2(float v, short& hi, short& lo) {
  hi = f2bf(v);
  lo = f2bf(v - bf2f(hi));
}
__device__ __forceinline__ float ldf(const void* p, long idx, bool isf32) {
  return isf32 ? ((const float*)p)[idx] : bf2f(((const short*)p)[idx]);
}

// dtype probe
__global__ void k_probe(const short* __restrict__ x, int* __restrict__ flag) {
  __shared__ int cnt;
  if (threadIdx.x == 0) cnt = 0;
  __syncthreads();
  short s = x[threadIdx.x];
  int e = (s >> 7) & 0xFF;
  int insane = (e != 0 && (e < 100 || e > 140)) ? 1 : 0;
  atomicAdd(&cnt, insane);
  __syncthreads();
  if (threadIdx.x == 0) *flag = (cnt > 64) ? 1 : 0;  // 1 = f32 inputs
}

// h0 = relu(x @ w_in + b_in) -> hi/lo planes
__global__ void k_input2(const void* __restrict__ x, const void* __restrict__ w,
                         const void* __restrict__ b, short* __restrict__ hhi,
                         short* __restrict__ hlo, const int* __restrict__ flag, int N) {
  bool isf32 = (*flag != 0);
  int idx = blockIdx.x * 256 + threadIdx.x;
  if (idx >= N * H) return;
  int v = idx >> 6, k = idx & 63;
  float acc = ldf(b, k, isf32);
#pragma unroll
  for (int d = 0; d < 3; ++d)
    acc += ldf(x, (long)v * 3 + d, isf32) * ldf(w, d * 64 + k, isf32);
  float r = fmaxf(acc, 0.f);
  short hi, lo; split2(r, hi, lo);
  hhi[idx] = hi; hlo[idx] = lo;
}

// ---------------- two-phase binned CSR build ----------------
// bucket(d) = (8*d)/N ; bucket x's windows are XCD-local in phase B (blockIdx&7).

// count bucket sizes (ballot-aggregated; 8 global atomics per block)
__global__ void k_bcount(const int* __restrict__ dstI, int* __restrict__ bcnt,
                         int E, int N) {
  __shared__ int cl[8];
  int tid = threadIdx.x;
  if (tid < 8) cl[tid] = 0;
  __syncthreads();
  int lane = tid & 63;
  for (int i = blockIdx.x * 256 + tid; i < E + 255; i += gridDim.x * 256) {
    bool v = i < E;
    int b = v ? (int)(((long)dstI[i] * 8) / N) : -1;
#pragma unroll
    for (int bb = 0; bb < 8; ++bb) {
      unsigned long long mask = __ballot(b == bb);
      if (mask && lane == (__ffsll((long long)mask) - 1))
        atomicAdd(&cl[bb], __popcll(mask));
    }
    if (i - tid + 256 >= E + 255) break;  // uniform exit after last full batch
  }
  __syncthreads();
  if (tid < 8) atomicAdd(&bcnt[tid], cl[tid]);
}

// tiny scan: bbase[0..8] from bcnt; also init bcur8
__global__ void k_bscan(const int* __restrict__ bcnt, int* __restrict__ bbase,
                        int* __restrict__ bcur8) {
  if (threadIdx.x == 0) {
    int s = 0;
    for (int b = 0; b < 8; ++b) { bbase[b] = s; bcur8[b] = s; s += bcnt[b]; }
    bbase[8] = s;
  }
}

// bin edges into bucket-contiguous pairs[] (coalesced writes). Two sweeps per
// block over its contiguous chunk; one global atomicAdd per bucket per block.
__global__ void k_bin(const int* __restrict__ srcI, const int* __restrict__ dstI,
                      int* __restrict__ bcur8, int2* __restrict__ pairs,
                      int E, int N) {
  __shared__ int cl[8], cur[8];
  int tid = threadIdx.x, lane = tid & 63;
  int chunk = (E + gridDim.x - 1) / gridDim.x;
  int s = blockIdx.x * chunk;
  int e = min(s + chunk, E);
  if (tid < 8) cl[tid] = 0;
  __syncthreads();
  // sweep 1: count
  for (int i0 = s; i0 < e; i0 += 256) {
    int i = i0 + tid;
    bool v = i < e;
    int b = v ? (int)(((long)dstI[i] * 8) / N) : -1;
#pragma unroll
    for (int bb = 0; bb < 8; ++bb) {
      unsigned long long mask = __ballot(b == bb);
      if (mask && lane == (__ffsll((long long)mask) - 1))
        atomicAdd(&cl[bb], __popcll(mask));
    }
  }
  __syncthreads();
  if (tid < 8) cur[tid] = atomicAdd(&bcur8[tid], cl[tid]);
  __syncthreads();
  // sweep 2: place
  for (int i0 = s; i0 < e; i0 += 256) {
    int i = i0 + tid;
    bool v = i < e;
    int d = v ? dstI[i] : 0;
    int sv = v ? srcI[i] : 0;
    int b = v ? (int)(((long)d * 8) / N) : -1;
#pragma unroll
    for (int bb = 0; bb < 8; ++bb) {
      unsigned long long mask = __ballot(b == bb);
      if (!mask) continue;
      int leader = __ffsll((long long)mask) - 1;
      int base = 0;
      if (lane == leader) base = atomicAdd(&cur[bb], __popcll(mask));
      base = __shfl(base, leader);
      if (b == bb) {
        int rank = __popcll(mask & ((1ULL << lane) - 1ULL));
        pairs[base + rank] = (int2){sv, d};
      }
    }
  }
}

// per-bucket deg histogram (XCD-local windows)
__global__ void k_hist_b(const int2* __restrict__ pairs, const int* __restrict__ bbase,
                         int* __restrict__ deg) {
  int x = blockIdx.x & 7, grp = blockIdx.x >> 3, ngrp = gridDim.x >> 3;
  int s = bbase[x], e = bbase[x + 1];
  for (int i = s + grp * 256 + threadIdx.x; i < e; i += ngrp * 256)
    atomicAdd(&deg[pairs[i].y], 1);
}

__global__ void k_scan_local(const int* __restrict__ deg, int* __restrict__ rowptr,
                             int* __restrict__ bsum, int N) {
  __shared__ int s[256];
  int tid = threadIdx.x;
  int base = blockIdx.x * 1024 + tid * 4;
  int v0 = (base + 0 < N) ? deg[base + 0] : 0;
  int v1 = (base + 1 < N) ? deg[base + 1] : 0;
  int v2 = (base + 2 < N) ? deg[base + 2] : 0;
  int v3 = (base + 3 < N) ? deg[base + 3] : 0;
  int tsum = v0 + v1 + v2 + v3;
  s[tid] = tsum;
  __syncthreads();
  for (int off = 1; off < 256; off <<= 1) {
    int x = (tid >= off) ? s[tid - off] : 0;
    __syncthreads();
    s[tid] += x;
    __syncthreads();
  }
  int excl = s[tid] - tsum;
  if (base + 0 < N) rowptr[base + 0] = excl;
  if (base + 1 < N) rowptr[base + 1] = excl + v0;
  if (base + 2 < N) rowptr[base + 2] = excl + v0 + v1;
  if (base + 3 < N) rowptr[base + 3] = excl + v0 + v1 + v2;
  if (tid == 255) bsum[blockIdx.x] = s[255];
}

__global__ void k_scan_block(const int* __restrict__ bsum, int* __restrict__ bexcl, int nb) {
  __shared__ int s[256];
  int tid = threadIdx.x;
  int v = (tid < nb) ? bsum[tid] : 0;
  s[tid] = v;
  __syncthreads();
  for (int off = 1; off < 256; off <<= 1) {
    int x = (tid >= off) ? s[tid - off] : 0;
    __syncthreads();
    s[tid] += x;
    __syncthreads();
  }
  bexcl[tid] = s[tid] - v;
}

__global__ void k_scan_add(int* __restrict__ rowptr, int* __restrict__ cursor,
                           const int* __restrict__ bexcl, int N, int E) {
  int i = blockIdx.x * 256 + threadIdx.x;
  if (i < N) {
    int v = rowptr[i] + bexcl[i >> 10];
    rowptr[i] = v;
    cursor[i] = v;
  }
  if (i == N) rowptr[N] = E;
}

// per-bucket CSR scatter (XCD-local deg/cursor/srcS windows)
__global__ void k_scatter_b(const int2* __restrict__ pairs, const int* __restrict__ bbase,
                            int* __restrict__ cursor, int* __restrict__ srcS) {
  int x = blockIdx.x & 7, grp = blockIdx.x >> 3, ngrp = gridDim.x >> 3;
  int s = bbase[x], e = bbase[x + 1];
  for (int i = s + grp * 256 + threadIdx.x; i < e; i += ngrp * 256) {
    int2 pr = pairs[i];
    int p = atomicAdd(&cursor[pr.y], 1);
    srcS[p] = pr.x;
  }
}

// ---------------- dense per-node message MLP (layer 0 only) ----------------
__global__ __launch_bounds__(256) void k_mlp(
    const short* __restrict__ hhi, const short* __restrict__ hlo,
    const void* __restrict__ W1, const void* __restrict__ B1,
    const void* __restrict__ W2, long oW, long oB,
    short* __restrict__ M, const int* __restrict__ flag, int N) {
  __shared__ short w1hi[64 * PADW], w1lo[64 * PADW];
  __shared__ short w2hi[64 * PADW], w2lo[64 * PADW];
  __shared__ float b1s[64];
  __shared__ float tbuf[4][16 * PADT];

  bool isf32 = (*flag != 0);
  int tid = threadIdx.x;
  for (int idx = tid; idx < 4096; idx += 256) {
    int j = idx >> 6, k = idx & 63;
    short hi, lo;
    split2(ldf(W1, oW + idx, isf32), hi, lo);
    w1hi[k * PADW + j] = hi; w1lo[k * PADW + j] = lo;
    split2(ldf(W2, oW + idx, isf32), hi, lo);
    w2hi[k * PADW + j] = hi; w2lo[k * PADW + j] = lo;
  }
  if (tid < 64) b1s[tid] = ldf(B1, oB + tid, isf32);
  __syncthreads();

  const int wave = tid >> 6, lane = tid & 63;
  const int m = lane & 15, quad = lane >> 4;
  float* tb = tbuf[wave];

  for (int nb = blockIdx.x * 64; nb < N; nb += gridDim.x * 64) {
    const int nBase = nb + wave * 16;
    int node = nBase + m;
    int nc = node < N ? node : N - 1;

    short8 fhi[2], flo[2];
    fhi[0] = *(const short8*)(hhi + (long)nc * H + quad * 8);
    fhi[1] = *(const short8*)(hhi + (long)nc * H + 32 + quad * 8);
    flo[0] = *(const short8*)(hlo + (long)nc * H + quad * 8);
    flo[1] = *(const short8*)(hlo + (long)nc * H + 32 + quad * 8);

    floatx4 acc[4];
#pragma unroll
    for (int t = 0; t < 4; ++t) acc[t] = (floatx4){0.f, 0.f, 0.f, 0.f};
#pragma unroll
    for (int t = 0; t < 4; ++t) {
      const short* whi = &w1hi[(t * 16 + m) * PADW + quad * 8];
      const short* wlo = &w1lo[(t * 16 + m) * PADW + quad * 8];
      acc[t] = MFMA(fhi[0], *(const short8*)(whi), acc[t]);
      acc[t] = MFMA(fhi[1], *(const short8*)(whi + 32), acc[t]);
      acc[t] = MFMA(flo[0], *(const short8*)(whi), acc[t]);
      acc[t] = MFMA(flo[1], *(const short8*)(whi + 32), acc[t]);
      acc[t] = MFMA(fhi[0], *(const short8*)(wlo), acc[t]);
      acc[t] = MFMA(fhi[1], *(const short8*)(wlo + 32), acc[t]);
    }

#pragma unroll
    for (int t = 0; t < 4; ++t) {
      int col = t * 16 + m;
      float bb = b1s[col];
#pragma unroll
      for (int r = 0; r < 4; ++r)
        tb[(quad * 4 + r) * PADT + col] = fmaxf(acc[t][r] + bb, 0.f);
    }

    float av[16];
    *(floatx4*)(av + 0)  = *(const floatx4*)(&tb[m * PADT + quad * 8]);
    *(floatx4*)(av + 4)  = *(const floatx4*)(&tb[m * PADT + quad * 8 + 4]);
    *(floatx4*)(av + 8)  = *(const floatx4*)(&tb[m * PADT + 32 + quad * 8]);
    *(floatx4*)(av + 12) = *(const floatx4*)(&tb[m * PADT + 32 + quad * 8 + 4]);
    short8 thi0, tlo0, thi1, tlo1;
#pragma unroll
    for (int j = 0; j < 8; ++j) {
      short hi, lo;
      split2(av[j], hi, lo);     thi0[j] = hi; tlo0[j] = lo;
      split2(av[8 + j], hi, lo); thi1[j] = hi; tlo1[j] = lo;
    }

    floatx4 mac[4];
#pragma unroll
    for (int t = 0; t < 4; ++t) mac[t] = (floatx4){0.f, 0.f, 0.f, 0.f};
#pragma unroll
    for (int t = 0; t < 4; ++t) {
      const short* whi = &w2hi[(t * 16 + m) * PADW + quad * 8];
      const short* wlo = &w2lo[(t * 16 + m) * PADW + quad * 8];
      mac[t] = MFMA(thi0, *(const short8*)(whi), mac[t]);
      mac[t] = MFMA(thi1, *(const short8*)(whi + 32), mac[t]);
      mac[t] = MFMA(tlo0, *(const short8*)(whi), mac[t]);
      mac[t] = MFMA(tlo1, *(const short8*)(whi + 32), mac[t]);
      mac[t] = MFMA(thi0, *(const short8*)(wlo), mac[t]);
      mac[t] = MFMA(thi1, *(const short8*)(wlo + 32), mac[t]);
    }

#pragma unroll
    for (int t = 0; t < 4; ++t) {
      int col = t * 16 + m;
#pragma unroll
      for (int r = 0; r < 4; ++r) {
        int nrow = nBase + quad * 4 + r;
        if (nrow < N) M[(long)nrow * H + col] = f2bf(mac[t][r]);
      }
    }
  }
}

// ---------------- gather-sum: agg[d] = sum_seg M[src] + deg*b2 ----------------
__global__ __launch_bounds__(256) void k_gather(
    const short* __restrict__ M, const int* __restrict__ rowptr,
    const int* __restrict__ srcS, const void* __restrict__ B2, long oB,
    short* __restrict__ agg, const int* __restrict__ flag, int N, int totWaves) {
  __shared__ float b2s[64];
  bool isf32 = (*flag != 0);
  if (threadIdx.x < 64) b2s[threadIdx.x] = ldf(B2, oB + threadIdx.x, isf32);
  __syncthreads();
  const int wave = threadIdx.x >> 6, lane = threadIdx.x & 63;
  const int g = lane >> 4, l = lane & 15;
  float b2v[4];
#pragma unroll
  for (int j = 0; j < 4; ++j) b2v[j] = b2s[l * 4 + j];

  const int gw = blockIdx.x * 4 + wave;
  const int nTask = (N + 3) >> 2;
  for (int task = gw; task < nTask; task += totWaves) {
    int n = task * 4 + g;
    bool valid = n < N;
    int nc = valid ? n : N - 1;
    int rs = rowptr[nc], re = rowptr[nc + 1];
    if (!valid) { rs = 0; re = 0; }
    float a0 = 0.f, a1 = 0.f, a2 = 0.f, a3 = 0.f;
    for (int e = rs; e < re; e += 8) {
      int sv[8];
#pragma unroll
      for (int u = 0; u < 8; ++u) {
        int c = e + u < re ? e + u : re - 1;
        sv[u] = srcS[c];
      }
      short4v rr[8];
#pragma unroll
      for (int u = 0; u < 8; ++u)
        rr[u] = *(const short4v*)(M + (long)sv[u] * H + l * 4);
#pragma unroll
      for (int u = 0; u < 8; ++u) {
        if (e + u < re) {
          a0 += bf2f(rr[u][0]); a1 += bf2f(rr[u][1]);
          a2 += bf2f(rr[u][2]); a3 += bf2f(rr[u][3]);
        }
      }
    }
    if (valid) {
      float dv = (float)(re - rs);
      short4v o;
      o[0] = f2bf(a0 + dv * b2v[0]);
      o[1] = f2bf(a1 + dv * b2v[1]);
      o[2] = f2bf(a2 + dv * b2v[2]);
      o[3] = f2bf(a3 + dv * b2v[3]);
      *(short4v*)(agg + (long)n * H + l * 4) = o;
    }
  }
}

// ---------------- persistent fused update + next-layer message MLP ----------------
__global__ __launch_bounds__(256) void k_updm(
    short* __restrict__ hhi, short* __restrict__ hlo, const short* __restrict__ agg,
    const void* __restrict__ U1, const void* __restrict__ UB1,
    const void* __restrict__ U2, const void* __restrict__ UB2,
    const void* __restrict__ G, const void* __restrict__ Bb,
    const void* __restrict__ Mm, const void* __restrict__ Vv,
    const void* __restrict__ W1m, const void* __restrict__ B1m,
    const void* __restrict__ W2m,
    long oU, long oW, long oB, long oWn, long oBn,
    short* __restrict__ Mout, const int* __restrict__ flag, int N, int doMsg) {
  __shared__ short u1h[64 * PADU];
  __shared__ short u2h[64 * PADW];
  __shared__ short m1h[64 * PADW];
  __shared__ short m2h[64 * PADW];
  __shared__ float b1s[64], b2s[64], scl[64], sft[64], mb1[64];
  __shared__ float tbuf[4][16 * PADT];

  bool isf32 = (*flag != 0);
  int tid = threadIdx.x;
  for (int idx = tid; idx < 8192; idx += 256) {
    int j = idx >> 6, k = idx & 63;
    u1h[k * PADU + j] = f2bf(ldf(U1, oU + idx, isf32));
  }
  for (int idx = tid; idx < 4096; idx += 256) {
    int j = idx >> 6, k = idx & 63;
    u2h[k * PADW + j] = f2bf(ldf(U2, oW + idx, isf32));
    m1h[k * PADW + j] = f2bf(ldf(W1m, oWn + idx, isf32));
    m2h[k * PADW + j] = f2bf(ldf(W2m, oWn + idx, isf32));
  }
  if (tid < 64) {
    b1s[tid] = ldf(UB1, oB + tid, isf32);
    b2s[tid] = ldf(UB2, oB + tid, isf32);
    float s = ldf(G, oB + tid, isf32) * rsqrtf(ldf(Vv, oB + tid, isf32) + 1e-5f);
    scl[tid] = s;
    sft[tid] = ldf(Bb, oB + tid, isf32) - ldf(Mm, oB + tid, isf32) * s;
    mb1[tid] = ldf(B1m, oBn + tid, isf32);
  }
  __syncthreads();

  const int wave = tid >> 6, lane = tid & 63;
  const int m = lane & 15, quad = lane >> 4;
  float* tb = tbuf[wave];

  for (int nb = blockIdx.x * 64; nb < N; nb += gridDim.x * 64) {
    const int nBase = nb + wave * 16;
    int node = nBase + m;
    int nc = node < N ? node : N - 1;

    short8 fhi[4], flo[2];
    fhi[0] = *(const short8*)(hhi + (long)nc * H + quad * 8);
    fhi[1] = *(const short8*)(hhi + (long)nc * H + 32 + quad * 8);
    flo[0] = *(const short8*)(hlo + (long)nc * H + quad * 8);
    flo[1] = *(const short8*)(hlo + (long)nc * H + 32 + quad * 8);
    fhi[2] = *(const short8*)(agg + (long)nc * H + quad * 8);
    fhi[3] = *(const short8*)(agg + (long)nc * H + 32 + quad * 8);

    floatx4 acc[4];
#pragma unroll
    for (int t = 0; t < 4; ++t) acc[t] = (floatx4){0.f, 0.f, 0.f, 0.f};
#pragma unroll
    for (int t = 0; t < 4; ++t) {
      const short* wp = &u1h[(t * 16 + m) * PADU + quad * 8];
#pragma unroll
      for (int c = 0; c < 4; ++c) {
        acc[t] = MFMA(fhi[c], *(const short8*)(wp + 32 * c), acc[t]);
        if (c < 2) acc[t] = MFMA(flo[c], *(const short8*)(wp + 32 * c), acc[t]);
      }
    }

#pragma unroll
    for (int t = 0; t < 4; ++t) {
      int col = t * 16 + m;
      float bb = b1s[col];
#pragma unroll
      for (int r = 0; r < 4; ++r)
        tb[(quad * 4 + r) * PADT + col] = fmaxf(acc[t][r] + bb, 0.f);
    }
    float av[16];
    *(floatx4*)(av + 0)  = *(const floatx4*)(&tb[m * PADT + quad * 8]);
    *(floatx4*)(av + 4)  = *(const floatx4*)(&tb[m * PADT + quad * 8 + 4]);
    *(floatx4*)(av + 8)  = *(const floatx4*)(&tb[m * PADT + 32 + quad * 8]);
    *(floatx4*)(av + 12) = *(const floatx4*)(&tb[m * PADT + 32 + quad * 8 + 4]);
    short8 thi[2], tlo[2];
#pragma unroll
    for (int j = 0; j < 8; ++j) {
      short hi, lo;
      split2(av[j], hi, lo);     thi[0][j] = hi; tlo[0][j] = lo;
      split2(av[8 + j], hi, lo); thi[1][j] = hi; tlo[1][j] = lo;
    }

    floatx4 mac[4];
#pragma unroll
    for (int t = 0; t < 4; ++t) mac[t] = (floatx4){0.f, 0.f, 0.f, 0.f};
#pragma unroll
    for (int t = 0; t < 4; ++t) {
      const short* wp = &u2h[(t * 16 + m) * PADW + quad * 8];
#pragma unroll
      for (int c = 0; c < 2; ++c) {
        mac[t] = MFMA(thi[c], *(const short8*)(wp + 32 * c), mac[t]);
        mac[t] = MFMA(tlo[c], *(const short8*)(wp + 32 * c), mac[t]);
      }
    }

#pragma unroll
    for (int t = 0; t < 4; ++t) {
      int col = t * 16 + m;
      float bb = b2s[col], ss = scl[col], ff = sft[col];
#pragma unroll
      for (int r = 0; r < 4; ++r) {
        int nrow = nBase + quad * 4 + r;
        float hn = 0.f;
        if (nrow < N) {
          long el = (long)nrow * H + col;
          float hv = (mac[t][r] + bb) * ss + ff;
          float ho = bf2f(hhi[el]) + bf2f(hlo[el]);
          hn = fmaxf(hv + ho, 0.f);
          short hi2, lo2; split2(hn, hi2, lo2);
          hhi[el] = hi2; hlo[el] = lo2;
        }
        tb[(quad * 4 + r) * PADT + col] = hn;
      }
    }

    if (doMsg) {
      *(floatx4*)(av + 0)  = *(const floatx4*)(&tb[m * PADT + quad * 8]);
      *(floatx4*)(av + 4)  = *(const floatx4*)(&tb[m * PADT + quad * 8 + 4]);
      *(floatx4*)(av + 8)  = *(const floatx4*)(&tb[m * PADT + 32 + quad * 8]);
      *(floatx4*)(av + 12) = *(const floatx4*)(&tb[m * PADT + 32 + quad * 8 + 4]);
#pragma unroll
      for (int j = 0; j < 8; ++j) {
        short hi, lo;
        split2(av[j], hi, lo);     thi[0][j] = hi; tlo[0][j] = lo;
        split2(av[8 + j], hi, lo); thi[1][j] = hi; tlo[1][j] = lo;
      }

#pragma unroll
      for (int t = 0; t < 4; ++t) acc[t] = (floatx4){0.f, 0.f, 0.f, 0.f};
#pragma unroll
      for (int t = 0; t < 4; ++t) {
        const short* wp = &m1h[(t * 16 + m) * PADW + quad * 8];
#pragma unroll
        for (int c = 0; c < 2; ++c) {
          acc[t] = MFMA(thi[c], *(const short8*)(wp + 32 * c), acc[t]);
          acc[t] = MFMA(tlo[c], *(const short8*)(wp + 32 * c), acc[t]);
        }
      }

#pragma unroll
      for (int t = 0; t < 4; ++t) {
        int col = t * 16 + m;
        float bb = mb1[col];
#pragma unroll
        for (int r = 0; r < 4; ++r)
          tb[(quad * 4 + r) * PADT + col] = fmaxf(acc[t][r] + bb, 0.f);
      }
      *(floatx4*)(av + 0)  = *(const floatx4*)(&tb[m * PADT + quad * 8]);
      *(floatx4*)(av + 4)  = *(const floatx4*)(&tb[m * PADT + quad * 8 + 4]);
      *(floatx4*)(av + 8)  = *(const floatx4*)(&tb[m * PADT + 32 + quad * 8]);
      *(floatx4*)(av + 12) = *(const floatx4*)(&tb[m * PADT + 32 + quad * 8 + 4]);
#pragma unroll
      for (int j = 0; j < 8; ++j) {
        short hi, lo;
        split2(av[j], hi, lo);     thi[0][j] = hi; tlo[0][j] = lo;
        split2(av[8 + j], hi, lo); thi[1][j] = hi; tlo[1][j] = lo;
      }

#pragma unroll
      for (int t = 0; t < 4; ++t) mac[t] = (floatx4){0.f, 0.f, 0.f, 0.f};
#pragma unroll
      for (int t = 0; t < 4; ++t) {
        const short* wp = &m2h[(t * 16 + m) * PADW + quad * 8];
#pragma unroll
        for (int c = 0; c < 2; ++c) {
          mac[t] = MFMA(thi[c], *(const short8*)(wp + 32 * c), mac[t]);
          mac[t] = MFMA(tlo[c], *(const short8*)(wp + 32 * c), mac[t]);
        }
      }

#pragma unroll
      for (int t = 0; t < 4; ++t) {
        int col = t * 16 + m;
#pragma unroll
        for (int r = 0; r < 4; ++r) {
          int nrow = nBase + quad * 4 + r;
          if (nrow < N) Mout[(long)nrow * H + col] = f2bf(mac[t][r]);
        }
      }
    }
  }
}

// readout from hi/lo planes
__global__ __launch_bounds__(256) void k_out2(
    const short* __restrict__ hhi, const short* __restrict__ hlo,
    const void* __restrict__ W1, const void* __restrict__ B1,
    const void* __restrict__ W2, const void* __restrict__ B2,
    void* __restrict__ out, const int* __restrict__ flag, int NQ) {
  __shared__ float w1s[64 * 32];
  __shared__ float b1sh[32], w2s[32];
  bool isf32 = (*flag != 0);
  int tid = threadIdx.x;
  for (int idx = tid; idx < 2048; idx += 256) w1s[idx] = ldf(W1, idx, isf32);
  if (tid < 32) { b1sh[tid] = ldf(B1, tid, isf32); w2s[tid] = ldf(W2, tid, isf32); }
  __syncthreads();
  int v = blockIdx.x * 256 + tid;
  if (v >= NQ) return;
  float hr[64];
#pragma unroll
  for (int j = 0; j < 64; ++j)
    hr[j] = bf2f(hhi[(long)v * H + j]) + bf2f(hlo[(long)v * H + j]);
  float accum = ldf(B2, 0, isf32);
#pragma unroll 4
  for (int k = 0; k < 32; ++k) {
    float t = b1sh[k];
#pragma unroll
    for (int j = 0; j < 64; ++j) t += hr[j] * w1s[j * 32 + k];
    accum += fmaxf(t, 0.f) * w2s[k];
  }
  if (isf32) ((float*)out)[v] = accum;
  else ((short*)out)[v] = f2bf(accum);
}

extern "C" void kernel_launch(void* const* d_in, const int* in_sizes, int n_in,
                              void* d_out, int out_size, void* d_ws, size_t ws_size,
                              hipStream_t stream) {
  const void* x      = d_in[0];
  const int*  ei     = (const int*)d_in[1];
  const void* w_in   = d_in[3];
  const void* b_in   = d_in[4];
  const void* msg_w1 = d_in[5];
  const void* msg_b1 = d_in[6];
  const void* msg_w2 = d_in[7];
  const void* msg_b2 = d_in[8];
  const void* upd_w1 = d_in[9];
  const void* upd_b1 = d_in[10];
  const void* upd_w2 = d_in[11];
  const void* upd_b2 = d_in[12];
  const void* bn_g   = d_in[13];
  const void* bn_b   = d_in[14];
  const void* bn_m   = d_in[15];
  const void* bn_v   = d_in[16];
  const void* out_w1 = d_in[17];
  const void* out_b1 = d_in[18];
  const void* out_w2 = d_in[19];
  const void* out_b2 = d_in[20];

  const int N = in_sizes[0] / 3;
  const int E = in_sizes[1] / 2;
  const int L = in_sizes[5] / (H * H);
  const int* srcI = ei;
  const int* dstI = ei + E;

  // workspace layout (256B-aligned slots)
  size_t off = 0;
  auto alloc = [&](size_t bytes) { size_t o = off; off += (bytes + 255) & ~(size_t)255; return o; };
  size_t mSize = (size_t)N * H * sizeof(short);
  size_t pSize = (size_t)E * sizeof(int2);
  size_t o_flag   = alloc(256);   // [0]=flag, [8..15]=bcnt, [16..24]=bbase, [32..39]=bcur8
  size_t o_hhi    = alloc((size_t)N * H * sizeof(short));
  size_t o_hlo    = alloc((size_t)N * H * sizeof(short));
  size_t o_agg    = alloc((size_t)N * H * sizeof(short));
  size_t o_M      = alloc(mSize > pSize ? mSize : pSize);  // M overlays pairs
  size_t o_rowptr = alloc((size_t)(N + 1) * sizeof(int));
  size_t o_cursor = alloc((size_t)N * sizeof(int));
  size_t o_bsum   = alloc(256 * sizeof(int));
  size_t o_bexcl  = alloc(256 * sizeof(int));
  size_t o_srcS   = alloc((size_t)E * sizeof(int));
  const int NB = (N + 1023) >> 10;

  char* ws = (char*)d_ws;
  int*   flag   = (int*)(ws + o_flag);
  int*   bcnt   = flag + 8;
  int*   bbase  = flag + 16;
  int*   bcur8  = flag + 32;
  short* hhi    = (short*)(ws + o_hhi);
  short* hlo    = (short*)(ws + o_hlo);
  short* aggS   = (short*)(ws + o_agg);
  short* Mbuf   = (short*)(ws + o_M);
  int2*  pairs  = (int2*)(ws + o_M);
  int*   rowptr = (int*)(ws + o_rowptr);
  int*   deg    = (int*)(ws + o_cursor);
  int*   bsum   = (int*)(ws + o_bsum);
  int*   bexcl  = (int*)(ws + o_bexcl);
  int*   srcS   = (int*)(ws + o_srcS);

  hipMemsetAsync(flag, 0, 256, stream);  // zeroes flag + bcnt/bbase/bcur8
  k_probe<<<1, 256, 0, stream>>>((const short*)x, flag);
  k_input2<<<(N * H + 255) / 256, 256, 0, stream>>>(x, w_in, b_in, hhi, hlo, flag, N);

  // binned CSR build
  hipMemsetAsync(deg, 0, (size_t)N * sizeof(int), stream);
  k_bcount<<<512, 256, 0, stream>>>(dstI, bcnt, E, N);
  k_bscan<<<1, 64, 0, stream>>>(bcnt, bbase, bcur8);
  k_bin<<<512, 256, 0, stream>>>(srcI, dstI, bcur8, pairs, E, N);
  k_hist_b<<<512, 256, 0, stream>>>(pairs, bbase, deg);
  k_scan_local<<<NB, 256, 0, stream>>>(deg, rowptr, bsum, N);
  k_scan_block<<<1, 256, 0, stream>>>(bsum, bexcl, NB);
  k_scan_add<<<(N + 256) / 256, 256, 0, stream>>>(rowptr, deg, bexcl, N, E);
  k_scatter_b<<<512, 256, 0, stream>>>(pairs, bbase, deg, srcS);

  // M_0 (full-precision standalone MLP, persistent) — after pairs is dead
  k_mlp<<<768, 256, 0, stream>>>(hhi, hlo,
      msg_w1, msg_b1, msg_w2, 0, 0, Mbuf, flag, N);

  const int GB = 2048;
  const int UB = 512;  // persistent k_updm: 2 blocks/CU (LDS ~70KB)
  for (int i = 0; i < L; ++i) {
    long oW = (long)i * H * H, oU = (long)i * 2 * H * H, oB = (long)i * H;
    int doMsg = (i + 1 < L) ? 1 : 0;
    long oWn = doMsg ? (long)(i + 1) * H * H : 0;
    long oBn = doMsg ? (long)(i + 1) * H : 0;
    k_gather<<<GB, 256, 0, stream>>>(Mbuf, rowptr, srcS,
        msg_b2, oB, aggS, flag, N, GB * 4);
    k_updm<<<UB, 256, 0, stream>>>(hhi, hlo, aggS,
        upd_w1, upd_b1, upd_w2, upd_b2, bn_g, bn_b, bn_m, bn_v,
        msg_w1, msg_b1, msg_w2,
        oU, oW, oB, oWn, oBn, Mbuf, flag, N, doMsg);
  }
  k_out2<<<(out_size + 255) / 256, 256, 0, stream>>>(hhi, hlo,
      out_w1, out_b1, out_w2, out_b2, d_out, flag, out_size);
}

// Round 12
// 713.649 us; speedup vs baseline: 1.0965x; 1.0965x over previous
//
#include <hip/hip_runtime.h>
#include <hip/hip_bf16.h>

#define H 64
#define PADW 88    // bf16 plane stride (shorts)
#define PADT 68    // f32 transpose-buffer stride (floats)

typedef __attribute__((ext_vector_type(8))) short short8;
typedef __attribute__((ext_vector_type(4))) short short4v;
typedef __attribute__((ext_vector_type(4))) float floatx4;

#define MFMA(a, b, c) __builtin_amdgcn_mfma_f32_16x16x32_bf16(a, b, c, 0, 0, 0)

__device__ __forceinline__ float bf2f(short s) {
  union { unsigned int u; float f; } v;
  v.u = ((unsigned int)(unsigned short)s) << 16;
  return v.f;
}
__device__ __forceinline__ short f2bf(float f) {
  union { float f; unsigned int u; } v; v.f = f;
  unsigned int r = v.u + 0x7fffu + ((v.u >> 16) & 1u);  // RNE
  return (short)(r >> 16);
}
__device__ __forceinline__ void split2(float v, short& hi, short& lo) {
  hi = f2bf(v);
  lo = f2bf(v - bf2f(hi));
}
__device__ __forceinline__ float ldf(const void* p, long idx, bool isf32) {
  return isf32 ? ((const float*)p)[idx] : bf2f(((const short*)p)[idx]);
}

// dtype probe
__global__ void k_probe(const short* __restrict__ x, int* __restrict__ flag) {
  __shared__ int cnt;
  if (threadIdx.x == 0) cnt = 0;
  __syncthreads();
  short s = x[threadIdx.x];
  int e = (s >> 7) & 0xFF;
  int insane = (e != 0 && (e < 100 || e > 140)) ? 1 : 0;
  atomicAdd(&cnt, insane);
  __syncthreads();
  if (threadIdx.x == 0) *flag = (cnt > 64) ? 1 : 0;  // 1 = f32 inputs
}

// h0 = relu(x @ w_in + b_in) -> hi/lo planes
__global__ void k_input2(const void* __restrict__ x, const void* __restrict__ w,
                         const void* __restrict__ b, short* __restrict__ hhi,
                         short* __restrict__ hlo, const int* __restrict__ flag, int N) {
  bool isf32 = (*flag != 0);
  int idx = blockIdx.x * 256 + threadIdx.x;
  if (idx >= N * H) return;
  int v = idx >> 6, k = idx & 63;
  float acc = ldf(b, k, isf32);
#pragma unroll
  for (int d = 0; d < 3; ++d)
    acc += ldf(x, (long)v * 3 + d, isf32) * ldf(w, d * 64 + k, isf32);
  float r = fmaxf(acc, 0.f);
  short hi, lo; split2(r, hi, lo);
  hhi[idx] = hi; hlo[idx] = lo;
}

// ---------------- CSR build (round-10 proven) ----------------

__global__ void k_hist_x(const int* __restrict__ dstI, int* __restrict__ deg,
                         int E, int N) {
  const int xcd = blockIdx.x & 7;
  const int grp = blockIdx.x >> 3;
  const int ngrp = gridDim.x >> 3;
  const int lo = (int)(((long)N * xcd) >> 3);
  const int hi = (int)(((long)N * (xcd + 1)) >> 3);
  for (int e = grp * 256 + threadIdx.x; e < E; e += ngrp * 256) {
    int d = dstI[e];
    if (d >= lo && d < hi) atomicAdd(&deg[d], 1);
  }
}

__global__ void k_scan_local(const int* __restrict__ deg, int* __restrict__ rowptr,
                             int* __restrict__ bsum, int N) {
  __shared__ int s[256];
  int tid = threadIdx.x;
  int base = blockIdx.x * 1024 + tid * 4;
  int v0 = (base + 0 < N) ? deg[base + 0] : 0;
  int v1 = (base + 1 < N) ? deg[base + 1] : 0;
  int v2 = (base + 2 < N) ? deg[base + 2] : 0;
  int v3 = (base + 3 < N) ? deg[base + 3] : 0;
  int tsum = v0 + v1 + v2 + v3;
  s[tid] = tsum;
  __syncthreads();
  for (int off = 1; off < 256; off <<= 1) {
    int x = (tid >= off) ? s[tid - off] : 0;
    __syncthreads();
    s[tid] += x;
    __syncthreads();
  }
  int excl = s[tid] - tsum;
  if (base + 0 < N) rowptr[base + 0] = excl;
  if (base + 1 < N) rowptr[base + 1] = excl + v0;
  if (base + 2 < N) rowptr[base + 2] = excl + v0 + v1;
  if (base + 3 < N) rowptr[base + 3] = excl + v0 + v1 + v2;
  if (tid == 255) bsum[blockIdx.x] = s[255];
}

__global__ void k_scan_block(const int* __restrict__ bsum, int* __restrict__ bexcl, int nb) {
  __shared__ int s[256];
  int tid = threadIdx.x;
  int v = (tid < nb) ? bsum[tid] : 0;
  s[tid] = v;
  __syncthreads();
  for (int off = 1; off < 256; off <<= 1) {
    int x = (tid >= off) ? s[tid - off] : 0;
    __syncthreads();
    s[tid] += x;
    __syncthreads();
  }
  bexcl[tid] = s[tid] - v;
}

__global__ void k_scan_add(int* __restrict__ rowptr, int* __restrict__ cursor,
                           const int* __restrict__ bexcl, int N, int E) {
  int i = blockIdx.x * 256 + threadIdx.x;
  if (i < N) {
    int v = rowptr[i] + bexcl[i >> 10];
    rowptr[i] = v;
    cursor[i] = v;
  }
  if (i == N) rowptr[N] = E;
}

__global__ void k_scatter_x(const int* __restrict__ srcI, const int* __restrict__ dstI,
                            int* __restrict__ cursor, int* __restrict__ srcS,
                            int E, int N) {
  const int xcd = blockIdx.x & 7;
  const int grp = blockIdx.x >> 3;
  const int ngrp = gridDim.x >> 3;
  const int lo = (int)(((long)N * xcd) >> 3);
  const int hi = (int)(((long)N * (xcd + 1)) >> 3);
  for (int e = grp * 256 + threadIdx.x; e < E; e += ngrp * 256) {
    int d = dstI[e];
    if (d >= lo && d < hi) {
      int p = atomicAdd(&cursor[d], 1);
      srcS[p] = srcI[e];
    }
  }
}

// ---------------- dense per-node message MLP (layer 0 only) ----------------
__global__ __launch_bounds__(256) void k_mlp(
    const short* __restrict__ hhi, const short* __restrict__ hlo,
    const void* __restrict__ W1, const void* __restrict__ B1,
    const void* __restrict__ W2, long oW, long oB,
    short* __restrict__ M, const int* __restrict__ flag, int N) {
  __shared__ short w1hi[64 * PADW], w1lo[64 * PADW];
  __shared__ short w2hi[64 * PADW], w2lo[64 * PADW];
  __shared__ float b1s[64];
  __shared__ float tbuf[4][16 * PADT];

  bool isf32 = (*flag != 0);
  int tid = threadIdx.x;
  for (int idx = tid; idx < 4096; idx += 256) {
    int j = idx >> 6, k = idx & 63;
    short hi, lo;
    split2(ldf(W1, oW + idx, isf32), hi, lo);
    w1hi[k * PADW + j] = hi; w1lo[k * PADW + j] = lo;
    split2(ldf(W2, oW + idx, isf32), hi, lo);
    w2hi[k * PADW + j] = hi; w2lo[k * PADW + j] = lo;
  }
  if (tid < 64) b1s[tid] = ldf(B1, oB + tid, isf32);
  __syncthreads();

  const int wave = tid >> 6, lane = tid & 63;
  const int m = lane & 15, quad = lane >> 4;
  float* tb = tbuf[wave];

  for (int nb = blockIdx.x * 64; nb < N; nb += gridDim.x * 64) {
    const int nBase = nb + wave * 16;
    int node = nBase + m;
    int nc = node < N ? node : N - 1;

    short8 fhi[2], flo[2];
    fhi[0] = *(const short8*)(hhi + (long)nc * H + quad * 8);
    fhi[1] = *(const short8*)(hhi + (long)nc * H + 32 + quad * 8);
    flo[0] = *(const short8*)(hlo + (long)nc * H + quad * 8);
    flo[1] = *(const short8*)(hlo + (long)nc * H + 32 + quad * 8);

    floatx4 acc[4];
#pragma unroll
    for (int t = 0; t < 4; ++t) acc[t] = (floatx4){0.f, 0.f, 0.f, 0.f};
#pragma unroll
    for (int t = 0; t < 4; ++t) {
      const short* whi = &w1hi[(t * 16 + m) * PADW + quad * 8];
      const short* wlo = &w1lo[(t * 16 + m) * PADW + quad * 8];
      acc[t] = MFMA(fhi[0], *(const short8*)(whi), acc[t]);
      acc[t] = MFMA(fhi[1], *(const short8*)(whi + 32), acc[t]);
      acc[t] = MFMA(flo[0], *(const short8*)(whi), acc[t]);
      acc[t] = MFMA(flo[1], *(const short8*)(whi + 32), acc[t]);
      acc[t] = MFMA(fhi[0], *(const short8*)(wlo), acc[t]);
      acc[t] = MFMA(fhi[1], *(const short8*)(wlo + 32), acc[t]);
    }

#pragma unroll
    for (int t = 0; t < 4; ++t) {
      int col = t * 16 + m;
      float bb = b1s[col];
#pragma unroll
      for (int r = 0; r < 4; ++r)
        tb[(quad * 4 + r) * PADT + col] = fmaxf(acc[t][r] + bb, 0.f);
    }

    float av[16];
    *(floatx4*)(av + 0)  = *(const floatx4*)(&tb[m * PADT + quad * 8]);
    *(floatx4*)(av + 4)  = *(const floatx4*)(&tb[m * PADT + quad * 8 + 4]);
    *(floatx4*)(av + 8)  = *(const floatx4*)(&tb[m * PADT + 32 + quad * 8]);
    *(floatx4*)(av + 12) = *(const floatx4*)(&tb[m * PADT + 32 + quad * 8 + 4]);
    short8 thi0, tlo0, thi1, tlo1;
#pragma unroll
    for (int j = 0; j < 8; ++j) {
      short hi, lo;
      split2(av[j], hi, lo);     thi0[j] = hi; tlo0[j] = lo;
      split2(av[8 + j], hi, lo); thi1[j] = hi; tlo1[j] = lo;
    }

    floatx4 mac[4];
#pragma unroll
    for (int t = 0; t < 4; ++t) mac[t] = (floatx4){0.f, 0.f, 0.f, 0.f};
#pragma unroll
    for (int t = 0; t < 4; ++t) {
      const short* whi = &w2hi[(t * 16 + m) * PADW + quad * 8];
      const short* wlo = &w2lo[(t * 16 + m) * PADW + quad * 8];
      mac[t] = MFMA(thi0, *(const short8*)(whi), mac[t]);
      mac[t] = MFMA(thi1, *(const short8*)(whi + 32), mac[t]);
      mac[t] = MFMA(tlo0, *(const short8*)(whi), mac[t]);
      mac[t] = MFMA(tlo1, *(const short8*)(whi + 32), mac[t]);
      mac[t] = MFMA(thi0, *(const short8*)(wlo), mac[t]);
      mac[t] = MFMA(thi1, *(const short8*)(wlo + 32), mac[t]);
    }

#pragma unroll
    for (int t = 0; t < 4; ++t) {
      int col = t * 16 + m;
#pragma unroll
      for (int r = 0; r < 4; ++r) {
        int nrow = nBase + quad * 4 + r;
        if (nrow < N) M[(long)nrow * H + col] = f2bf(mac[t][r]);
      }
    }
  }
}

// ---------------- gather-sum: agg[d] = sum_seg M[src] + deg*b2 ----------------
__global__ __launch_bounds__(256) void k_gather(
    const short* __restrict__ M, const int* __restrict__ rowptr,
    const int* __restrict__ srcS, const void* __restrict__ B2, long oB,
    short* __restrict__ agg, const int* __restrict__ flag, int N, int totWaves) {
  __shared__ float b2s[64];
  bool isf32 = (*flag != 0);
  if (threadIdx.x < 64) b2s[threadIdx.x] = ldf(B2, oB + threadIdx.x, isf32);
  __syncthreads();
  const int wave = threadIdx.x >> 6, lane = threadIdx.x & 63;
  const int g = lane >> 4, l = lane & 15;
  float b2v[4];
#pragma unroll
  for (int j = 0; j < 4; ++j) b2v[j] = b2s[l * 4 + j];

  const int gw = blockIdx.x * 4 + wave;
  const int nTask = (N + 3) >> 2;
  for (int task = gw; task < nTask; task += totWaves) {
    int n = task * 4 + g;
    bool valid = n < N;
    int nc = valid ? n : N - 1;
    int rs = rowptr[nc], re = rowptr[nc + 1];
    if (!valid) { rs = 0; re = 0; }
    float a0 = 0.f, a1 = 0.f, a2 = 0.f, a3 = 0.f;
    for (int e = rs; e < re; e += 8) {
      int sv[8];
#pragma unroll
      for (int u = 0; u < 8; ++u) {
        int c = e + u < re ? e + u : re - 1;
        sv[u] = srcS[c];
      }
      short4v rr[8];
#pragma unroll
      for (int u = 0; u < 8; ++u)
        rr[u] = *(const short4v*)(M + (long)sv[u] * H + l * 4);
#pragma unroll
      for (int u = 0; u < 8; ++u) {
        if (e + u < re) {
          a0 += bf2f(rr[u][0]); a1 += bf2f(rr[u][1]);
          a2 += bf2f(rr[u][2]); a3 += bf2f(rr[u][3]);
        }
      }
    }
    if (valid) {
      float dv = (float)(re - rs);
      short4v o;
      o[0] = f2bf(a0 + dv * b2v[0]);
      o[1] = f2bf(a1 + dv * b2v[1]);
      o[2] = f2bf(a2 + dv * b2v[2]);
      o[3] = f2bf(a3 + dv * b2v[3]);
      *(short4v*)(agg + (long)n * H + l * 4) = o;
    }
  }
}

// ---------------- persistent fused update + next-layer message MLP ----------------
// Fragment-major weight staging (zero padding, conflict-free 16B lane reads):
// u1f 16KB (K=128), u2f 8KB, m1f 8KB in LDS; m2 weights in REGISTERS (staged
// through m1f then restaged). LDS ~50.3KB -> 3 blocks/CU. Numerics identical
// to round-10 (same weight values, only addressing changed).
__global__ __launch_bounds__(256) void k_updm(
    short* __restrict__ hhi, short* __restrict__ hlo, const short* __restrict__ agg,
    const void* __restrict__ U1, const void* __restrict__ UB1,
    const void* __restrict__ U2, const void* __restrict__ UB2,
    const void* __restrict__ G, const void* __restrict__ Bb,
    const void* __restrict__ Mm, const void* __restrict__ Vv,
    const void* __restrict__ W1m, const void* __restrict__ B1m,
    const void* __restrict__ W2m,
    long oU, long oW, long oB, long oWn, long oBn,
    short* __restrict__ Mout, const int* __restrict__ flag, int N, int doMsg) {
  __shared__ short u1f[8192];   // frag-major K=128
  __shared__ short u2f[4096];   // frag-major K=64
  __shared__ short m1f[4096];   // frag-major K=64 (temporarily holds m2 for reg hoist)
  __shared__ float b1s[64], b2s[64], scl[64], sft[64], mb1[64];
  __shared__ float tbuf[4][16 * PADT];

  bool isf32 = (*flag != 0);
  int tid = threadIdx.x;
  const int wave = tid >> 6, lane = tid & 63;
  const int m = lane & 15, quad = lane >> 4;

  // pass 1: stage m2 frag-major into m1f, hoist to registers
  for (int idx = tid; idx < 4096; idx += 256) {
    int in = idx >> 6, n = idx & 63;
    int t = n >> 4, mm = n & 15, c = in >> 5, qq = (in >> 3) & 3, jj = in & 7;
    m1f[(((t * 2 + c) * 64) + (qq * 16 + mm)) * 8 + jj] = f2bf(ldf(W2m, oWn + idx, isf32));
  }
  __syncthreads();
  short8 m2r[4][2];
#pragma unroll
  for (int t = 0; t < 4; ++t)
#pragma unroll
    for (int c = 0; c < 2; ++c)
      m2r[t][c] = *(const short8*)&m1f[(((t * 2 + c) * 64) + lane) * 8];
  __syncthreads();

  // pass 2: stage u1, u2, m1, biases
  for (int idx = tid; idx < 8192; idx += 256) {
    int in = idx >> 6, n = idx & 63;
    int t = n >> 4, mm = n & 15, c = in >> 5, qq = (in >> 3) & 3, jj = in & 7;
    u1f[(((t * 4 + c) * 64) + (qq * 16 + mm)) * 8 + jj] = f2bf(ldf(U1, oU + idx, isf32));
  }
  for (int idx = tid; idx < 4096; idx += 256) {
    int in = idx >> 6, n = idx & 63;
    int t = n >> 4, mm = n & 15, c = in >> 5, qq = (in >> 3) & 3, jj = in & 7;
    int fi = (((t * 2 + c) * 64) + (qq * 16 + mm)) * 8 + jj;
    u2f[fi] = f2bf(ldf(U2, oW + idx, isf32));
    m1f[fi] = f2bf(ldf(W1m, oWn + idx, isf32));
  }
  if (tid < 64) {
    b1s[tid] = ldf(UB1, oB + tid, isf32);
    b2s[tid] = ldf(UB2, oB + tid, isf32);
    float s = ldf(G, oB + tid, isf32) * rsqrtf(ldf(Vv, oB + tid, isf32) + 1e-5f);
    scl[tid] = s;
    sft[tid] = ldf(Bb, oB + tid, isf32) - ldf(Mm, oB + tid, isf32) * s;
    mb1[tid] = ldf(B1m, oBn + tid, isf32);
  }
  __syncthreads();

  float* tb = tbuf[wave];

  for (int nb = blockIdx.x * 64; nb < N; nb += gridDim.x * 64) {
    const int nBase = nb + wave * 16;
    int node = nBase + m;
    int nc = node < N ? node : N - 1;

    short8 fhi[4], flo[2];
    fhi[0] = *(const short8*)(hhi + (long)nc * H + quad * 8);
    fhi[1] = *(const short8*)(hhi + (long)nc * H + 32 + quad * 8);
    flo[0] = *(const short8*)(hlo + (long)nc * H + quad * 8);
    flo[1] = *(const short8*)(hlo + (long)nc * H + 32 + quad * 8);
    fhi[2] = *(const short8*)(agg + (long)nc * H + quad * 8);
    fhi[3] = *(const short8*)(agg + (long)nc * H + 32 + quad * 8);

    // upd GEMM1 (K=128, weights hi-only, frag-major)
    floatx4 acc[4];
#pragma unroll
    for (int t = 0; t < 4; ++t) acc[t] = (floatx4){0.f, 0.f, 0.f, 0.f};
#pragma unroll
    for (int t = 0; t < 4; ++t) {
#pragma unroll
      for (int c = 0; c < 4; ++c) {
        const short8 w = *(const short8*)&u1f[(((t * 4 + c) * 64) + lane) * 8];
        acc[t] = MFMA(fhi[c], w, acc[t]);
        if (c < 2) acc[t] = MFMA(flo[c], w, acc[t]);
      }
    }

#pragma unroll
    for (int t = 0; t < 4; ++t) {
      int col = t * 16 + m;
      float bb = b1s[col];
#pragma unroll
      for (int r = 0; r < 4; ++r)
        tb[(quad * 4 + r) * PADT + col] = fmaxf(acc[t][r] + bb, 0.f);
    }
    float av[16];
    *(floatx4*)(av + 0)  = *(const floatx4*)(&tb[m * PADT + quad * 8]);
    *(floatx4*)(av + 4)  = *(const floatx4*)(&tb[m * PADT + quad * 8 + 4]);
    *(floatx4*)(av + 8)  = *(const floatx4*)(&tb[m * PADT + 32 + quad * 8]);
    *(floatx4*)(av + 12) = *(const floatx4*)(&tb[m * PADT + 32 + quad * 8 + 4]);
    short8 thi[2], tlo[2];
#pragma unroll
    for (int j = 0; j < 8; ++j) {
      short hi, lo;
      split2(av[j], hi, lo);     thi[0][j] = hi; tlo[0][j] = lo;
      split2(av[8 + j], hi, lo); thi[1][j] = hi; tlo[1][j] = lo;
    }

    // upd GEMM2 (weights hi-only, frag-major)
    floatx4 mac[4];
#pragma unroll
    for (int t = 0; t < 4; ++t) mac[t] = (floatx4){0.f, 0.f, 0.f, 0.f};
#pragma unroll
    for (int t = 0; t < 4; ++t) {
#pragma unroll
      for (int c = 0; c < 2; ++c) {
        const short8 w = *(const short8*)&u2f[(((t * 2 + c) * 64) + lane) * 8];
        mac[t] = MFMA(thi[c], w, mac[t]);
        mac[t] = MFMA(tlo[c], w, mac[t]);
      }
    }

    // epilogue: BN + residual relu; write h planes; deposit h_new into tbuf
#pragma unroll
    for (int t = 0; t < 4; ++t) {
      int col = t * 16 + m;
      float bb = b2s[col], ss = scl[col], ff = sft[col];
#pragma unroll
      for (int r = 0; r < 4; ++r) {
        int nrow = nBase + quad * 4 + r;
        float hn = 0.f;
        if (nrow < N) {
          long el = (long)nrow * H + col;
          float hv = (mac[t][r] + bb) * ss + ff;
          float ho = bf2f(hhi[el]) + bf2f(hlo[el]);
          hn = fmaxf(hv + ho, 0.f);
          short hi2, lo2; split2(hn, hi2, lo2);
          hhi[el] = hi2; hlo[el] = lo2;
        }
        tb[(quad * 4 + r) * PADT + col] = hn;
      }
    }

    if (doMsg) {
      *(floatx4*)(av + 0)  = *(const floatx4*)(&tb[m * PADT + quad * 8]);
      *(floatx4*)(av + 4)  = *(const floatx4*)(&tb[m * PADT + quad * 8 + 4]);
      *(floatx4*)(av + 8)  = *(const floatx4*)(&tb[m * PADT + 32 + quad * 8]);
      *(floatx4*)(av + 12) = *(const floatx4*)(&tb[m * PADT + 32 + quad * 8 + 4]);
#pragma unroll
      for (int j = 0; j < 8; ++j) {
        short hi, lo;
        split2(av[j], hi, lo);     thi[0][j] = hi; tlo[0][j] = lo;
        split2(av[8 + j], hi, lo); thi[1][j] = hi; tlo[1][j] = lo;
      }

      // msg GEMM1 (weights hi-only, frag-major; h hi+lo)
#pragma unroll
      for (int t = 0; t < 4; ++t) acc[t] = (floatx4){0.f, 0.f, 0.f, 0.f};
#pragma unroll
      for (int t = 0; t < 4; ++t) {
#pragma unroll
        for (int c = 0; c < 2; ++c) {
          const short8 w = *(const short8*)&m1f[(((t * 2 + c) * 64) + lane) * 8];
          acc[t] = MFMA(thi[c], w, acc[t]);
          acc[t] = MFMA(tlo[c], w, acc[t]);
        }
      }

#pragma unroll
      for (int t = 0; t < 4; ++t) {
        int col = t * 16 + m;
        float bb = mb1[col];
#pragma unroll
        for (int r = 0; r < 4; ++r)
          tb[(quad * 4 + r) * PADT + col] = fmaxf(acc[t][r] + bb, 0.f);
      }
      *(floatx4*)(av + 0)  = *(const floatx4*)(&tb[m * PADT + quad * 8]);
      *(floatx4*)(av + 4)  = *(const floatx4*)(&tb[m * PADT + quad * 8 + 4]);
      *(floatx4*)(av + 8)  = *(const floatx4*)(&tb[m * PADT + 32 + quad * 8]);
      *(floatx4*)(av + 12) = *(const floatx4*)(&tb[m * PADT + 32 + quad * 8 + 4]);
#pragma unroll
      for (int j = 0; j < 8; ++j) {
        short hi, lo;
        split2(av[j], hi, lo);     thi[0][j] = hi; tlo[0][j] = lo;
        split2(av[8 + j], hi, lo); thi[1][j] = hi; tlo[1][j] = lo;
      }

      // msg GEMM2 (weights hi-only, from REGISTERS)
#pragma unroll
      for (int t = 0; t < 4; ++t) mac[t] = (floatx4){0.f, 0.f, 0.f, 0.f};
#pragma unroll
      for (int t = 0; t < 4; ++t) {
#pragma unroll
        for (int c = 0; c < 2; ++c) {
          mac[t] = MFMA(thi[c], m2r[t][c], mac[t]);
          mac[t] = MFMA(tlo[c], m2r[t][c], mac[t]);
        }
      }

#pragma unroll
      for (int t = 0; t < 4; ++t) {
        int col = t * 16 + m;
#pragma unroll
        for (int r = 0; r < 4; ++r) {
          int nrow = nBase + quad * 4 + r;
          if (nrow < N) Mout[(long)nrow * H + col] = f2bf(mac[t][r]);
        }
      }
    }
  }
}

// readout from hi/lo planes
__global__ __launch_bounds__(256) void k_out2(
    const short* __restrict__ hhi, const short* __restrict__ hlo,
    const void* __restrict__ W1, const void* __restrict__ B1,
    const void* __restrict__ W2, const void* __restrict__ B2,
    void* __restrict__ out, const int* __restrict__ flag, int NQ) {
  __shared__ float w1s[64 * 32];
  __shared__ float b1sh[32], w2s[32];
  bool isf32 = (*flag != 0);
  int tid = threadIdx.x;
  for (int idx = tid; idx < 2048; idx += 256) w1s[idx] = ldf(W1, idx, isf32);
  if (tid < 32) { b1sh[tid] = ldf(B1, tid, isf32); w2s[tid] = ldf(W2, tid, isf32); }
  __syncthreads();
  int v = blockIdx.x * 256 + tid;
  if (v >= NQ) return;
  float hr[64];
#pragma unroll
  for (int j = 0; j < 64; ++j)
    hr[j] = bf2f(hhi[(long)v * H + j]) + bf2f(hlo[(long)v * H + j]);
  float accum = ldf(B2, 0, isf32);
#pragma unroll 4
  for (int k = 0; k < 32; ++k) {
    float t = b1sh[k];
#pragma unroll
    for (int j = 0; j < 64; ++j) t += hr[j] * w1s[j * 32 + k];
    accum += fmaxf(t, 0.f) * w2s[k];
  }
  if (isf32) ((float*)out)[v] = accum;
  else ((short*)out)[v] = f2bf(accum);
}

extern "C" void kernel_launch(void* const* d_in, const int* in_sizes, int n_in,
                              void* d_out, int out_size, void* d_ws, size_t ws_size,
                              hipStream_t stream) {
  const void* x      = d_in[0];
  const int*  ei     = (const int*)d_in[1];
  const void* w_in   = d_in[3];
  const void* b_in   = d_in[4];
  const void* msg_w1 = d_in[5];
  const void* msg_b1 = d_in[6];
  const void* msg_w2 = d_in[7];
  const void* msg_b2 = d_in[8];
  const void* upd_w1 = d_in[9];
  const void* upd_b1 = d_in[10];
  const void* upd_w2 = d_in[11];
  const void* upd_b2 = d_in[12];
  const void* bn_g   = d_in[13];
  const void* bn_b   = d_in[14];
  const void* bn_m   = d_in[15];
  const void* bn_v   = d_in[16];
  const void* out_w1 = d_in[17];
  const void* out_b1 = d_in[18];
  const void* out_w2 = d_in[19];
  const void* out_b2 = d_in[20];

  const int N = in_sizes[0] / 3;
  const int E = in_sizes[1] / 2;
  const int L = in_sizes[5] / (H * H);
  const int* srcI = ei;
  const int* dstI = ei + E;

  // workspace layout (256B-aligned slots)
  size_t off = 0;
  auto alloc = [&](size_t bytes) { size_t o = off; off += (bytes + 255) & ~(size_t)255; return o; };
  size_t o_flag   = alloc(256);
  size_t o_hhi    = alloc((size_t)N * H * sizeof(short));
  size_t o_hlo    = alloc((size_t)N * H * sizeof(short));
  size_t o_agg    = alloc((size_t)N * H * sizeof(short));
  size_t o_M      = alloc((size_t)N * H * sizeof(short));
  size_t o_rowptr = alloc((size_t)(N + 1) * sizeof(int));
  size_t o_cursor = alloc((size_t)N * sizeof(int));
  size_t o_bsum   = alloc(256 * sizeof(int));
  size_t o_bexcl  = alloc(256 * sizeof(int));
  size_t o_srcS   = alloc((size_t)E * sizeof(int));
  const int NB = (N + 1023) >> 10;

  char* ws = (char*)d_ws;
  int*   flag   = (int*)(ws + o_flag);
  short* hhi    = (short*)(ws + o_hhi);
  short* hlo    = (short*)(ws + o_hlo);
  short* aggS   = (short*)(ws + o_agg);
  short* Mbuf   = (short*)(ws + o_M);
  int*   rowptr = (int*)(ws + o_rowptr);
  int*   deg    = (int*)(ws + o_cursor);
  int*   bsum   = (int*)(ws + o_bsum);
  int*   bexcl  = (int*)(ws + o_bexcl);
  int*   srcS   = (int*)(ws + o_srcS);

  k_probe<<<1, 256, 0, stream>>>((const short*)x, flag);
  k_input2<<<(N * H + 255) / 256, 256, 0, stream>>>(x, w_in, b_in, hhi, hlo, flag, N);

  // CSR build (round-10 proven)
  hipMemsetAsync(deg, 0, (size_t)N * sizeof(int), stream);
  k_hist_x<<<8 * 128, 256, 0, stream>>>(dstI, deg, E, N);
  k_scan_local<<<NB, 256, 0, stream>>>(deg, rowptr, bsum, N);
  k_scan_block<<<1, 256, 0, stream>>>(bsum, bexcl, NB);
  k_scan_add<<<(N + 256) / 256, 256, 0, stream>>>(rowptr, deg, bexcl, N, E);
  k_scatter_x<<<8 * 128, 256, 0, stream>>>(srcI, dstI, deg, srcS, E, N);

  // M_0 (full-precision standalone MLP, persistent)
  k_mlp<<<768, 256, 0, stream>>>(hhi, hlo,
      msg_w1, msg_b1, msg_w2, 0, 0, Mbuf, flag, N);

  const int GB = 2048;
  const int UB = 768;  // persistent k_updm: 3 blocks/CU (LDS ~50.3KB)
  for (int i = 0; i < L; ++i) {
    long oW = (long)i * H * H, oU = (long)i * 2 * H * H, oB = (long)i * H;
    int doMsg = (i + 1 < L) ? 1 : 0;
    long oWn = doMsg ? (long)(i + 1) * H * H : 0;
    long oBn = doMsg ? (long)(i + 1) * H : 0;
    k_gather<<<GB, 256, 0, stream>>>(Mbuf, rowptr, srcS,
        msg_b2, oB, aggS, flag, N, GB * 4);
    k_updm<<<UB, 256, 0, stream>>>(hhi, hlo, aggS,
        upd_w1, upd_b1, upd_w2, upd_b2, bn_g, bn_b, bn_m, bn_v,
        msg_w1, msg_b1, msg_w2,
        oU, oW, oB, oWn, oBn, Mbuf, flag, N, doMsg);
  }
  k_out2<<<(out_size + 255) / 256, 256, 0, stream>>>(hhi, hlo,
      out_w1, out_b1, out_w2, out_b2, d_out, flag, out_size);
}

// Round 13
// 624.287 us; speedup vs baseline: 1.2535x; 1.1431x over previous
//
#include <hip/hip_runtime.h>
#include <hip/hip_bf16.h>

#define H 64
#define PADW 88    // bf16 plane stride (shorts)
#define PADT 68    // f32 transpose-buffer stride (floats)
#define CAP 10240  // k_sortb LDS src staging capacity (40KB)

typedef __attribute__((ext_vector_type(8))) short short8;
typedef __attribute__((ext_vector_type(4))) short short4v;
typedef __attribute__((ext_vector_type(4))) float floatx4;

#define MFMA(a, b, c) __builtin_amdgcn_mfma_f32_16x16x32_bf16(a, b, c, 0, 0, 0)

__device__ __forceinline__ float bf2f(short s) {
  union { unsigned int u; float f; } v;
  v.u = ((unsigned int)(unsigned short)s) << 16;
  return v.f;
}
__device__ __forceinline__ short f2bf(float f) {
  union { float f; unsigned int u; } v; v.f = f;
  unsigned int r = v.u + 0x7fffu + ((v.u >> 16) & 1u);  // RNE
  return (short)(r >> 16);
}
__device__ __forceinline__ void split2(float v, short& hi, short& lo) {
  hi = f2bf(v);
  lo = f2bf(v - bf2f(hi));
}
__device__ __forceinline__ float ldf(const void* p, long idx, bool isf32) {
  return isf32 ? ((const float*)p)[idx] : bf2f(((const short*)p)[idx]);
}

// dtype probe
__global__ void k_probe(const short* __restrict__ x, int* __restrict__ flag) {
  __shared__ int cnt;
  if (threadIdx.x == 0) cnt = 0;
  __syncthreads();
  short s = x[threadIdx.x];
  int e = (s >> 7) & 0xFF;
  int insane = (e != 0 && (e < 100 || e > 140)) ? 1 : 0;
  atomicAdd(&cnt, insane);
  __syncthreads();
  if (threadIdx.x == 0) *flag = (cnt > 64) ? 1 : 0;  // 1 = f32 inputs
}

// h0 = relu(x @ w_in + b_in) -> hi/lo planes
__global__ void k_input2(const void* __restrict__ x, const void* __restrict__ w,
                         const void* __restrict__ b, short* __restrict__ hhi,
                         short* __restrict__ hlo, const int* __restrict__ flag, int N) {
  bool isf32 = (*flag != 0);
  int idx = blockIdx.x * 256 + threadIdx.x;
  if (idx >= N * H) return;
  int v = idx >> 6, k = idx & 63;
  float acc = ldf(b, k, isf32);
#pragma unroll
  for (int d = 0; d < 3; ++d)
    acc += ldf(x, (long)v * 3 + d, isf32) * ldf(w, d * 64 + k, isf32);
  float r = fmaxf(acc, 0.f);
  short hi, lo; split2(r, hi, lo);
  hhi[idx] = hi; hlo[idx] = lo;
}

// ---------------- dense-write CSR build ----------------
// bucket(d) = d >> 8 (256-node windows); B = ceil(N/256) <= 1024.

// LDS-combined bucket histogram
__global__ void k_bcount(const int* __restrict__ dstI, int* __restrict__ bcnt, int E) {
  __shared__ int cl[1024];
  int tid = threadIdx.x;
  for (int t = tid; t < 1024; t += 256) cl[t] = 0;
  __syncthreads();
  for (int i = blockIdx.x * 256 + tid; i < E; i += gridDim.x * 256)
    atomicAdd(&cl[dstI[i] >> 8], 1);
  __syncthreads();
  for (int t = tid; t < 1024; t += 256)
    if (cl[t]) atomicAdd(&bcnt[t], cl[t]);
}

// one-block exclusive scan of bcnt[1024] -> bbase[0..1024], bcur = bbase
__global__ void k_bscan(const int* __restrict__ bcnt, int* __restrict__ bbase,
                        int* __restrict__ bcur) {
  __shared__ int s[256];
  int tid = threadIdx.x;
  int base = tid * 4;
  int v0 = bcnt[base], v1 = bcnt[base + 1], v2 = bcnt[base + 2], v3 = bcnt[base + 3];
  int tsum = v0 + v1 + v2 + v3;
  s[tid] = tsum;
  __syncthreads();
  for (int off = 1; off < 256; off <<= 1) {
    int x = (tid >= off) ? s[tid - off] : 0;
    __syncthreads();
    s[tid] += x;
    __syncthreads();
  }
  int excl = s[tid] - tsum;
  bbase[base] = excl;           bcur[base] = excl;
  bbase[base + 1] = excl + v0;  bcur[base + 1] = excl + v0;
  bbase[base + 2] = excl + v0 + v1;      bcur[base + 2] = excl + v0 + v1;
  bbase[base + 3] = excl + v0 + v1 + v2; bcur[base + 3] = excl + v0 + v1 + v2;
  if (tid == 255) bbase[1024] = s[255];
}

// bin edges into bucket-contiguous pairs[]; per-(block,bucket) runs are
// contiguous -> writes mostly dense.
__global__ void k_bin(const int* __restrict__ srcI, const int* __restrict__ dstI,
                      int* __restrict__ bcur, int2* __restrict__ pairs, int E) {
  __shared__ int cl[1024], cur[1024];
  int tid = threadIdx.x;
  int chunk = (E + gridDim.x - 1) / gridDim.x;
  int s = blockIdx.x * chunk;
  int e = min(s + chunk, E);
  for (int t = tid; t < 1024; t += 256) cl[t] = 0;
  __syncthreads();
  for (int i = s + tid; i < e; i += 256) atomicAdd(&cl[dstI[i] >> 8], 1);
  __syncthreads();
  for (int t = tid; t < 1024; t += 256)
    cur[t] = cl[t] ? atomicAdd(&bcur[t], cl[t]) : 0;
  __syncthreads();
  for (int i = s + tid; i < e; i += 256) {
    int d = dstI[i];
    int p = atomicAdd(&cur[d >> 8], 1);
    pairs[p] = (int2){srcI[i], d};
  }
}

// per-bucket counting sort: produces rowptr (dense writes) + srcS (dense flush
// from LDS staging). One block per bucket.
__global__ __launch_bounds__(256) void k_sortb(
    const int2* __restrict__ pairs, const int* __restrict__ bbase,
    int* __restrict__ rowptr, int* __restrict__ srcS, int N, int E, int B) {
  __shared__ int cnt[256], cur[256], s2[256];
  __shared__ int stage[CAP];
  int b = blockIdx.x, tid = threadIdx.x;
  int lo = b << 8;
  int W = min(256, N - lo);
  int s = bbase[b], e = bbase[b + 1];
  cnt[tid] = 0;
  __syncthreads();
  // sweep 1: window-local degree count
  for (int i = s + tid; i < e; i += 256)
    atomicAdd(&cnt[pairs[i].y - lo], 1);
  __syncthreads();
  // exclusive scan over W (<=256) counters
  int v = (tid < W) ? cnt[tid] : 0;
  s2[tid] = v;
  __syncthreads();
  for (int off = 1; off < 256; off <<= 1) {
    int x = (tid >= off) ? s2[tid - off] : 0;
    __syncthreads();
    s2[tid] += x;
    __syncthreads();
  }
  int excl = s2[tid] - v;
  if (tid < W) {
    rowptr[lo + tid] = s + excl;  // dense rowptr write
    cur[tid] = excl;
  }
  if (b == B - 1 && tid == 0) rowptr[N] = E;
  __syncthreads();
  // sweep 2: place src into LDS staging (global spill if bucket > CAP)
  for (int i = s + tid; i < e; i += 256) {
    int2 pr = pairs[i];
    int p = atomicAdd(&cur[pr.y - lo], 1);
    if (p < CAP) stage[p] = pr.x;
    else srcS[s + p] = pr.x;
  }
  __syncthreads();
  // dense coalesced flush
  int Sb = e - s;
  int lim = Sb < CAP ? Sb : CAP;
  for (int i = tid; i < lim; i += 256) srcS[s + i] = stage[i];
}

// ---------------- dense per-node message MLP (layer 0 only) ----------------
__global__ __launch_bounds__(256) void k_mlp(
    const short* __restrict__ hhi, const short* __restrict__ hlo,
    const void* __restrict__ W1, const void* __restrict__ B1,
    const void* __restrict__ W2, long oW, long oB,
    short* __restrict__ M, const int* __restrict__ flag, int N) {
  __shared__ short w1hi[64 * PADW], w1lo[64 * PADW];
  __shared__ short w2hi[64 * PADW], w2lo[64 * PADW];
  __shared__ float b1s[64];
  __shared__ float tbuf[4][16 * PADT];

  bool isf32 = (*flag != 0);
  int tid = threadIdx.x;
  for (int idx = tid; idx < 4096; idx += 256) {
    int j = idx >> 6, k = idx & 63;
    short hi, lo;
    split2(ldf(W1, oW + idx, isf32), hi, lo);
    w1hi[k * PADW + j] = hi; w1lo[k * PADW + j] = lo;
    split2(ldf(W2, oW + idx, isf32), hi, lo);
    w2hi[k * PADW + j] = hi; w2lo[k * PADW + j] = lo;
  }
  if (tid < 64) b1s[tid] = ldf(B1, oB + tid, isf32);
  __syncthreads();

  const int wave = tid >> 6, lane = tid & 63;
  const int m = lane & 15, quad = lane >> 4;
  float* tb = tbuf[wave];

  for (int nb = blockIdx.x * 64; nb < N; nb += gridDim.x * 64) {
    const int nBase = nb + wave * 16;
    int node = nBase + m;
    int nc = node < N ? node : N - 1;

    short8 fhi[2], flo[2];
    fhi[0] = *(const short8*)(hhi + (long)nc * H + quad * 8);
    fhi[1] = *(const short8*)(hhi + (long)nc * H + 32 + quad * 8);
    flo[0] = *(const short8*)(hlo + (long)nc * H + quad * 8);
    flo[1] = *(const short8*)(hlo + (long)nc * H + 32 + quad * 8);

    floatx4 acc[4];
#pragma unroll
    for (int t = 0; t < 4; ++t) acc[t] = (floatx4){0.f, 0.f, 0.f, 0.f};
#pragma unroll
    for (int t = 0; t < 4; ++t) {
      const short* whi = &w1hi[(t * 16 + m) * PADW + quad * 8];
      const short* wlo = &w1lo[(t * 16 + m) * PADW + quad * 8];
      acc[t] = MFMA(fhi[0], *(const short8*)(whi), acc[t]);
      acc[t] = MFMA(fhi[1], *(const short8*)(whi + 32), acc[t]);
      acc[t] = MFMA(flo[0], *(const short8*)(whi), acc[t]);
      acc[t] = MFMA(flo[1], *(const short8*)(whi + 32), acc[t]);
      acc[t] = MFMA(fhi[0], *(const short8*)(wlo), acc[t]);
      acc[t] = MFMA(fhi[1], *(const short8*)(wlo + 32), acc[t]);
    }

#pragma unroll
    for (int t = 0; t < 4; ++t) {
      int col = t * 16 + m;
      float bb = b1s[col];
#pragma unroll
      for (int r = 0; r < 4; ++r)
        tb[(quad * 4 + r) * PADT + col] = fmaxf(acc[t][r] + bb, 0.f);
    }

    float av[16];
    *(floatx4*)(av + 0)  = *(const floatx4*)(&tb[m * PADT + quad * 8]);
    *(floatx4*)(av + 4)  = *(const floatx4*)(&tb[m * PADT + quad * 8 + 4]);
    *(floatx4*)(av + 8)  = *(const floatx4*)(&tb[m * PADT + 32 + quad * 8]);
    *(floatx4*)(av + 12) = *(const floatx4*)(&tb[m * PADT + 32 + quad * 8 + 4]);
    short8 thi0, tlo0, thi1, tlo1;
#pragma unroll
    for (int j = 0; j < 8; ++j) {
      short hi, lo;
      split2(av[j], hi, lo);     thi0[j] = hi; tlo0[j] = lo;
      split2(av[8 + j], hi, lo); thi1[j] = hi; tlo1[j] = lo;
    }

    floatx4 mac[4];
#pragma unroll
    for (int t = 0; t < 4; ++t) mac[t] = (floatx4){0.f, 0.f, 0.f, 0.f};
#pragma unroll
    for (int t = 0; t < 4; ++t) {
      const short* whi = &w2hi[(t * 16 + m) * PADW + quad * 8];
      const short* wlo = &w2lo[(t * 16 + m) * PADW + quad * 8];
      mac[t] = MFMA(thi0, *(const short8*)(whi), mac[t]);
      mac[t] = MFMA(thi1, *(const short8*)(whi + 32), mac[t]);
      mac[t] = MFMA(tlo0, *(const short8*)(whi), mac[t]);
      mac[t] = MFMA(tlo1, *(const short8*)(whi + 32), mac[t]);
      mac[t] = MFMA(thi0, *(const short8*)(wlo), mac[t]);
      mac[t] = MFMA(thi1, *(const short8*)(wlo + 32), mac[t]);
    }

#pragma unroll
    for (int t = 0; t < 4; ++t) {
      int col = t * 16 + m;
#pragma unroll
      for (int r = 0; r < 4; ++r) {
        int nrow = nBase + quad * 4 + r;
        if (nrow < N) M[(long)nrow * H + col] = f2bf(mac[t][r]);
      }
    }
  }
}

// ---------------- gather-sum: agg[d] = sum_seg M[src] + deg*b2 ----------------
__global__ __launch_bounds__(256) void k_gather(
    const short* __restrict__ M, const int* __restrict__ rowptr,
    const int* __restrict__ srcS, const void* __restrict__ B2, long oB,
    short* __restrict__ agg, const int* __restrict__ flag, int N, int totWaves) {
  __shared__ float b2s[64];
  bool isf32 = (*flag != 0);
  if (threadIdx.x < 64) b2s[threadIdx.x] = ldf(B2, oB + threadIdx.x, isf32);
  __syncthreads();
  const int wave = threadIdx.x >> 6, lane = threadIdx.x & 63;
  const int g = lane >> 4, l = lane & 15;
  float b2v[4];
#pragma unroll
  for (int j = 0; j < 4; ++j) b2v[j] = b2s[l * 4 + j];

  const int gw = blockIdx.x * 4 + wave;
  const int nTask = (N + 3) >> 2;
  for (int task = gw; task < nTask; task += totWaves) {
    int n = task * 4 + g;
    bool valid = n < N;
    int nc = valid ? n : N - 1;
    int rs = rowptr[nc], re = rowptr[nc + 1];
    if (!valid) { rs = 0; re = 0; }
    float a0 = 0.f, a1 = 0.f, a2 = 0.f, a3 = 0.f;
    for (int e = rs; e < re; e += 8) {
      int sv[8];
#pragma unroll
      for (int u = 0; u < 8; ++u) {
        int c = e + u < re ? e + u : re - 1;
        sv[u] = srcS[c];
      }
      short4v rr[8];
#pragma unroll
      for (int u = 0; u < 8; ++u)
        rr[u] = *(const short4v*)(M + (long)sv[u] * H + l * 4);
#pragma unroll
      for (int u = 0; u < 8; ++u) {
        if (e + u < re) {
          a0 += bf2f(rr[u][0]); a1 += bf2f(rr[u][1]);
          a2 += bf2f(rr[u][2]); a3 += bf2f(rr[u][3]);
        }
      }
    }
    if (valid) {
      float dv = (float)(re - rs);
      short4v o;
      o[0] = f2bf(a0 + dv * b2v[0]);
      o[1] = f2bf(a1 + dv * b2v[1]);
      o[2] = f2bf(a2 + dv * b2v[2]);
      o[3] = f2bf(a3 + dv * b2v[3]);
      *(short4v*)(agg + (long)n * H + l * 4) = o;
    }
  }
}

// ---------------- persistent fused update + next-layer message MLP ----------------
// Frag-major weights (zero pad, conflict-free): u1f 16KB, u2f 8KB, m1f 8KB;
// m2 in registers. LDS ~50.3KB -> 3 blocks/CU.
__global__ __launch_bounds__(256) void k_updm(
    short* __restrict__ hhi, short* __restrict__ hlo, const short* __restrict__ agg,
    const void* __restrict__ U1, const void* __restrict__ UB1,
    const void* __restrict__ U2, const void* __restrict__ UB2,
    const void* __restrict__ G, const void* __restrict__ Bb,
    const void* __restrict__ Mm, const void* __restrict__ Vv,
    const void* __restrict__ W1m, const void* __restrict__ B1m,
    const void* __restrict__ W2m,
    long oU, long oW, long oB, long oWn, long oBn,
    short* __restrict__ Mout, const int* __restrict__ flag, int N, int doMsg) {
  __shared__ short u1f[8192];
  __shared__ short u2f[4096];
  __shared__ short m1f[4096];
  __shared__ float b1s[64], b2s[64], scl[64], sft[64], mb1[64];
  __shared__ float tbuf[4][16 * PADT];

  bool isf32 = (*flag != 0);
  int tid = threadIdx.x;
  const int wave = tid >> 6, lane = tid & 63;
  const int m = lane & 15, quad = lane >> 4;

  // pass 1: stage m2 frag-major into m1f, hoist to registers
  for (int idx = tid; idx < 4096; idx += 256) {
    int in = idx >> 6, n = idx & 63;
    int t = n >> 4, mm = n & 15, c = in >> 5, qq = (in >> 3) & 3, jj = in & 7;
    m1f[(((t * 2 + c) * 64) + (qq * 16 + mm)) * 8 + jj] = f2bf(ldf(W2m, oWn + idx, isf32));
  }
  __syncthreads();
  short8 m2r[4][2];
#pragma unroll
  for (int t = 0; t < 4; ++t)
#pragma unroll
    for (int c = 0; c < 2; ++c)
      m2r[t][c] = *(const short8*)&m1f[(((t * 2 + c) * 64) + lane) * 8];
  __syncthreads();

  // pass 2: stage u1, u2, m1, biases
  for (int idx = tid; idx < 8192; idx += 256) {
    int in = idx >> 6, n = idx & 63;
    int t = n >> 4, mm = n & 15, c = in >> 5, qq = (in >> 3) & 3, jj = in & 7;
    u1f[(((t * 4 + c) * 64) + (qq * 16 + mm)) * 8 + jj] = f2bf(ldf(U1, oU + idx, isf32));
  }
  for (int idx = tid; idx < 4096; idx += 256) {
    int in = idx >> 6, n = idx & 63;
    int t = n >> 4, mm = n & 15, c = in >> 5, qq = (in >> 3) & 3, jj = in & 7;
    int fi = (((t * 2 + c) * 64) + (qq * 16 + mm)) * 8 + jj;
    u2f[fi] = f2bf(ldf(U2, oW + idx, isf32));
    m1f[fi] = f2bf(ldf(W1m, oWn + idx, isf32));
  }
  if (tid < 64) {
    b1s[tid] = ldf(UB1, oB + tid, isf32);
    b2s[tid] = ldf(UB2, oB + tid, isf32);
    float s = ldf(G, oB + tid, isf32) * rsqrtf(ldf(Vv, oB + tid, isf32) + 1e-5f);
    scl[tid] = s;
    sft[tid] = ldf(Bb, oB + tid, isf32) - ldf(Mm, oB + tid, isf32) * s;
    mb1[tid] = ldf(B1m, oBn + tid, isf32);
  }
  __syncthreads();

  float* tb = tbuf[wave];

  for (int nb = blockIdx.x * 64; nb < N; nb += gridDim.x * 64) {
    const int nBase = nb + wave * 16;
    int node = nBase + m;
    int nc = node < N ? node : N - 1;

    short8 fhi[4], flo[2];
    fhi[0] = *(const short8*)(hhi + (long)nc * H + quad * 8);
    fhi[1] = *(const short8*)(hhi + (long)nc * H + 32 + quad * 8);
    flo[0] = *(const short8*)(hlo + (long)nc * H + quad * 8);
    flo[1] = *(const short8*)(hlo + (long)nc * H + 32 + quad * 8);
    fhi[2] = *(const short8*)(agg + (long)nc * H + quad * 8);
    fhi[3] = *(const short8*)(agg + (long)nc * H + 32 + quad * 8);

    floatx4 acc[4];
#pragma unroll
    for (int t = 0; t < 4; ++t) acc[t] = (floatx4){0.f, 0.f, 0.f, 0.f};
#pragma unroll
    for (int t = 0; t < 4; ++t) {
#pragma unroll
      for (int c = 0; c < 4; ++c) {
        const short8 w = *(const short8*)&u1f[(((t * 4 + c) * 64) + lane) * 8];
        acc[t] = MFMA(fhi[c], w, acc[t]);
        if (c < 2) acc[t] = MFMA(flo[c], w, acc[t]);
      }
    }

#pragma unroll
    for (int t = 0; t < 4; ++t) {
      int col = t * 16 + m;
      float bb = b1s[col];
#pragma unroll
      for (int r = 0; r < 4; ++r)
        tb[(quad * 4 + r) * PADT + col] = fmaxf(acc[t][r] + bb, 0.f);
    }
    float av[16];
    *(floatx4*)(av + 0)  = *(const floatx4*)(&tb[m * PADT + quad * 8]);
    *(floatx4*)(av + 4)  = *(const floatx4*)(&tb[m * PADT + quad * 8 + 4]);
    *(floatx4*)(av + 8)  = *(const floatx4*)(&tb[m * PADT + 32 + quad * 8]);
    *(floatx4*)(av + 12) = *(const floatx4*)(&tb[m * PADT + 32 + quad * 8 + 4]);
    short8 thi[2], tlo[2];
#pragma unroll
    for (int j = 0; j < 8; ++j) {
      short hi, lo;
      split2(av[j], hi, lo);     thi[0][j] = hi; tlo[0][j] = lo;
      split2(av[8 + j], hi, lo); thi[1][j] = hi; tlo[1][j] = lo;
    }

    floatx4 mac[4];
#pragma unroll
    for (int t = 0; t < 4; ++t) mac[t] = (floatx4){0.f, 0.f, 0.f, 0.f};
#pragma unroll
    for (int t = 0; t < 4; ++t) {
#pragma unroll
      for (int c = 0; c < 2; ++c) {
        const short8 w = *(const short8*)&u2f[(((t * 2 + c) * 64) + lane) * 8];
        mac[t] = MFMA(thi[c], w, mac[t]);
        mac[t] = MFMA(tlo[c], w, mac[t]);
      }
    }

#pragma unroll
    for (int t = 0; t < 4; ++t) {
      int col = t * 16 + m;
      float bb = b2s[col], ss = scl[col], ff = sft[col];
#pragma unroll
      for (int r = 0; r < 4; ++r) {
        int nrow = nBase + quad * 4 + r;
        float hn = 0.f;
        if (nrow < N) {
          long el = (long)nrow * H + col;
          float hv = (mac[t][r] + bb) * ss + ff;
          float ho = bf2f(hhi[el]) + bf2f(hlo[el]);
          hn = fmaxf(hv + ho, 0.f);
          short hi2, lo2; split2(hn, hi2, lo2);
          hhi[el] = hi2; hlo[el] = lo2;
        }
        tb[(quad * 4 + r) * PADT + col] = hn;
      }
    }

    if (doMsg) {
      *(floatx4*)(av + 0)  = *(const floatx4*)(&tb[m * PADT + quad * 8]);
      *(floatx4*)(av + 4)  = *(const floatx4*)(&tb[m * PADT + quad * 8 + 4]);
      *(floatx4*)(av + 8)  = *(const floatx4*)(&tb[m * PADT + 32 + quad * 8]);
      *(floatx4*)(av + 12) = *(const floatx4*)(&tb[m * PADT + 32 + quad * 8 + 4]);
#pragma unroll
      for (int j = 0; j < 8; ++j) {
        short hi, lo;
        split2(av[j], hi, lo);     thi[0][j] = hi; tlo[0][j] = lo;
        split2(av[8 + j], hi, lo); thi[1][j] = hi; tlo[1][j] = lo;
      }

#pragma unroll
      for (int t = 0; t < 4; ++t) acc[t] = (floatx4){0.f, 0.f, 0.f, 0.f};
#pragma unroll
      for (int t = 0; t < 4; ++t) {
#pragma unroll
        for (int c = 0; c < 2; ++c) {
          const short8 w = *(const short8*)&m1f[(((t * 2 + c) * 64) + lane) * 8];
          acc[t] = MFMA(thi[c], w, acc[t]);
          acc[t] = MFMA(tlo[c], w, acc[t]);
        }
      }

#pragma unroll
      for (int t = 0; t < 4; ++t) {
        int col = t * 16 + m;
        float bb = mb1[col];
#pragma unroll
        for (int r = 0; r < 4; ++r)
          tb[(quad * 4 + r) * PADT + col] = fmaxf(acc[t][r] + bb, 0.f);
      }
      *(floatx4*)(av + 0)  = *(const floatx4*)(&tb[m * PADT + quad * 8]);
      *(floatx4*)(av + 4)  = *(const floatx4*)(&tb[m * PADT + quad * 8 + 4]);
      *(floatx4*)(av + 8)  = *(const floatx4*)(&tb[m * PADT + 32 + quad * 8]);
      *(floatx4*)(av + 12) = *(const floatx4*)(&tb[m * PADT + 32 + quad * 8 + 4]);
#pragma unroll
      for (int j = 0; j < 8; ++j) {
        short hi, lo;
        split2(av[j], hi, lo);     thi[0][j] = hi; tlo[0][j] = lo;
        split2(av[8 + j], hi, lo); thi[1][j] = hi; tlo[1][j] = lo;
      }

#pragma unroll
      for (int t = 0; t < 4; ++t) mac[t] = (floatx4){0.f, 0.f, 0.f, 0.f};
#pragma unroll
      for (int t = 0; t < 4; ++t) {
#pragma unroll
        for (int c = 0; c < 2; ++c) {
          mac[t] = MFMA(thi[c], m2r[t][c], mac[t]);
          mac[t] = MFMA(tlo[c], m2r[t][c], mac[t]);
        }
      }

#pragma unroll
      for (int t = 0; t < 4; ++t) {
        int col = t * 16 + m;
#pragma unroll
        for (int r = 0; r < 4; ++r) {
          int nrow = nBase + quad * 4 + r;
          if (nrow < N) Mout[(long)nrow * H + col] = f2bf(mac[t][r]);
        }
      }
    }
  }
}

// readout from hi/lo planes
__global__ __launch_bounds__(256) void k_out2(
    const short* __restrict__ hhi, const short* __restrict__ hlo,
    const void* __restrict__ W1, const void* __restrict__ B1,
    const void* __restrict__ W2, const void* __restrict__ B2,
    void* __restrict__ out, const int* __restrict__ flag, int NQ) {
  __shared__ float w1s[64 * 32];
  __shared__ float b1sh[32], w2s[32];
  bool isf32 = (*flag != 0);
  int tid = threadIdx.x;
  for (int idx = tid; idx < 2048; idx += 256) w1s[idx] = ldf(W1, idx, isf32);
  if (tid < 32) { b1sh[tid] = ldf(B1, tid, isf32); w2s[tid] = ldf(W2, tid, isf32); }
  __syncthreads();
  int v = blockIdx.x * 256 + tid;
  if (v >= NQ) return;
  float hr[64];
#pragma unroll
  for (int j = 0; j < 64; ++j)
    hr[j] = bf2f(hhi[(long)v * H + j]) + bf2f(hlo[(long)v * H + j]);
  float accum = ldf(B2, 0, isf32);
#pragma unroll 4
  for (int k = 0; k < 32; ++k) {
    float t = b1sh[k];
#pragma unroll
    for (int j = 0; j < 64; ++j) t += hr[j] * w1s[j * 32 + k];
    accum += fmaxf(t, 0.f) * w2s[k];
  }
  if (isf32) ((float*)out)[v] = accum;
  else ((short*)out)[v] = f2bf(accum);
}

extern "C" void kernel_launch(void* const* d_in, const int* in_sizes, int n_in,
                              void* d_out, int out_size, void* d_ws, size_t ws_size,
                              hipStream_t stream) {
  const void* x      = d_in[0];
  const int*  ei     = (const int*)d_in[1];
  const void* w_in   = d_in[3];
  const void* b_in   = d_in[4];
  const void* msg_w1 = d_in[5];
  const void* msg_b1 = d_in[6];
  const void* msg_w2 = d_in[7];
  const void* msg_b2 = d_in[8];
  const void* upd_w1 = d_in[9];
  const void* upd_b1 = d_in[10];
  const void* upd_w2 = d_in[11];
  const void* upd_b2 = d_in[12];
  const void* bn_g   = d_in[13];
  const void* bn_b   = d_in[14];
  const void* bn_m   = d_in[15];
  const void* bn_v   = d_in[16];
  const void* out_w1 = d_in[17];
  const void* out_b1 = d_in[18];
  const void* out_w2 = d_in[19];
  const void* out_b2 = d_in[20];

  const int N = in_sizes[0] / 3;
  const int E = in_sizes[1] / 2;
  const int L = in_sizes[5] / (H * H);
  const int* srcI = ei;
  const int* dstI = ei + E;
  const int B = (N + 255) >> 8;  // dst buckets (<=1024 for N<=262144)

  // workspace layout (256B-aligned slots)
  size_t off = 0;
  auto alloc = [&](size_t bytes) { size_t o = off; off += (bytes + 255) & ~(size_t)255; return o; };
  size_t mSize = (size_t)N * H * sizeof(short);
  size_t pSize = (size_t)E * sizeof(int2);
  size_t o_flag   = alloc(256);
  size_t o_bcnt   = alloc(1024 * sizeof(int));
  size_t o_bbase  = alloc(1025 * sizeof(int));
  size_t o_bcur   = alloc(1024 * sizeof(int));
  size_t o_hhi    = alloc((size_t)N * H * sizeof(short));
  size_t o_hlo    = alloc((size_t)N * H * sizeof(short));
  size_t o_agg    = alloc((size_t)N * H * sizeof(short));
  size_t o_M      = alloc(mSize > pSize ? mSize : pSize);  // M overlays pairs
  size_t o_rowptr = alloc((size_t)(N + 1) * sizeof(int));
  size_t o_srcS   = alloc((size_t)E * sizeof(int));

  char* ws = (char*)d_ws;
  int*   flag   = (int*)(ws + o_flag);
  int*   bcnt   = (int*)(ws + o_bcnt);
  int*   bbase  = (int*)(ws + o_bbase);
  int*   bcur   = (int*)(ws + o_bcur);
  short* hhi    = (short*)(ws + o_hhi);
  short* hlo    = (short*)(ws + o_hlo);
  short* aggS   = (short*)(ws + o_agg);
  short* Mbuf   = (short*)(ws + o_M);
  int2*  pairs  = (int2*)(ws + o_M);
  int*   rowptr = (int*)(ws + o_rowptr);
  int*   srcS   = (int*)(ws + o_srcS);

  k_probe<<<1, 256, 0, stream>>>((const short*)x, flag);
  k_input2<<<(N * H + 255) / 256, 256, 0, stream>>>(x, w_in, b_in, hhi, hlo, flag, N);

  // dense-write CSR build
  hipMemsetAsync(bcnt, 0, 1024 * sizeof(int), stream);
  k_bcount<<<256, 256, 0, stream>>>(dstI, bcnt, E);
  k_bscan<<<1, 256, 0, stream>>>(bcnt, bbase, bcur);
  k_bin<<<256, 256, 0, stream>>>(srcI, dstI, bcur, pairs, E);
  k_sortb<<<B, 256, 0, stream>>>(pairs, bbase, rowptr, srcS, N, E, B);

  // M_0 (full-precision standalone MLP, persistent) — after pairs is dead
  k_mlp<<<768, 256, 0, stream>>>(hhi, hlo,
      msg_w1, msg_b1, msg_w2, 0, 0, Mbuf, flag, N);

  const int GB = 2048;
  const int UB = 768;  // persistent k_updm: 3 blocks/CU (LDS ~50.3KB)
  for (int i = 0; i < L; ++i) {
    long oW = (long)i * H * H, oU = (long)i * 2 * H * H, oB = (long)i * H;
    int doMsg = (i + 1 < L) ? 1 : 0;
    long oWn = doMsg ? (long)(i + 1) * H * H : 0;
    long oBn = doMsg ? (long)(i + 1) * H : 0;
    k_gather<<<GB, 256, 0, stream>>>(Mbuf, rowptr, srcS,
        msg_b2, oB, aggS, flag, N, GB * 4);
    k_updm<<<UB, 256, 0, stream>>>(hhi, hlo, aggS,
        upd_w1, upd_b1, upd_w2, upd_b2, bn_g, bn_b, bn_m, bn_v,
        msg_w1, msg_b1, msg_w2,
        oU, oW, oB, oWn, oBn, Mbuf, flag, N, doMsg);
  }
  k_out2<<<(out_size + 255) / 256, 256, 0, stream>>>(hhi, hlo,
      out_w1, out_b1, out_w2, out_b2, d_out, flag, out_size);
}

// Round 14
// 551.617 us; speedup vs baseline: 1.4186x; 1.1317x over previous
//
#include <hip/hip_runtime.h>
#include <hip/hip_bf16.h>

#define H 64
#define PADW 88    // bf16 plane stride (shorts)
#define PADT 68    // f32 transpose-buffer stride (floats)
#define CAP 10240  // k_sortb LDS src staging capacity (40KB)
#define WSTRIDE 20480  // prepped weights per layer (shorts): u1(8192)|u2(4096)|m1(4096)|m2(4096)

typedef __attribute__((ext_vector_type(8))) short short8;
typedef __attribute__((ext_vector_type(4))) short short4v;
typedef __attribute__((ext_vector_type(4))) float floatx4;

#define MFMA(a, b, c) __builtin_amdgcn_mfma_f32_16x16x32_bf16(a, b, c, 0, 0, 0)

__device__ __forceinline__ float bf2f(short s) {
  union { unsigned int u; float f; } v;
  v.u = ((unsigned int)(unsigned short)s) << 16;
  return v.f;
}
__device__ __forceinline__ short f2bf(float f) {
  union { float f; unsigned int u; } v; v.f = f;
  unsigned int r = v.u + 0x7fffu + ((v.u >> 16) & 1u);  // RNE
  return (short)(r >> 16);
}
__device__ __forceinline__ void split2(float v, short& hi, short& lo) {
  hi = f2bf(v);
  lo = f2bf(v - bf2f(hi));
}
__device__ __forceinline__ float ldf(const void* p, long idx, bool isf32) {
  return isf32 ? ((const float*)p)[idx] : bf2f(((const short*)p)[idx]);
}

// dtype probe
__global__ void k_probe(const short* __restrict__ x, int* __restrict__ flag) {
  __shared__ int cnt;
  if (threadIdx.x == 0) cnt = 0;
  __syncthreads();
  short s = x[threadIdx.x];
  int e = (s >> 7) & 0xFF;
  int insane = (e != 0 && (e < 100 || e > 140)) ? 1 : 0;
  atomicAdd(&cnt, insane);
  __syncthreads();
  if (threadIdx.x == 0) *flag = (cnt > 64) ? 1 : 0;  // 1 = f32 inputs
}

// h0 = relu(x @ w_in + b_in) -> hi/lo planes
__global__ void k_input2(const void* __restrict__ x, const void* __restrict__ w,
                         const void* __restrict__ b, short* __restrict__ hhi,
                         short* __restrict__ hlo, const int* __restrict__ flag, int N) {
  bool isf32 = (*flag != 0);
  int idx = blockIdx.x * 256 + threadIdx.x;
  if (idx >= N * H) return;
  int v = idx >> 6, k = idx & 63;
  float acc = ldf(b, k, isf32);
#pragma unroll
  for (int d = 0; d < 3; ++d)
    acc += ldf(x, (long)v * 3 + d, isf32) * ldf(w, d * 64 + k, isf32);
  float r = fmaxf(acc, 0.f);
  short hi, lo; split2(r, hi, lo);
  hhi[idx] = hi; hlo[idx] = lo;
}

// ---------------- one-time weight prep: frag-major bf16 bank ----------------
// block b converts layer b: u1(K=128) | u2 | m1 | m2 (all hi-only bf16).
__global__ void k_prep(const void* __restrict__ U1, const void* __restrict__ U2,
                       const void* __restrict__ W1m, const void* __restrict__ W2m,
                       short* __restrict__ prep, const int* __restrict__ flag) {
  bool isf32 = (*flag != 0);
  int i = blockIdx.x;
  short* p = prep + (long)i * WSTRIDE;
  long oU = (long)i * 8192, oW = (long)i * 4096;
  for (int idx = threadIdx.x; idx < 8192; idx += 256) {
    int in = idx >> 6, n = idx & 63;
    int t = n >> 4, mm = n & 15, c = in >> 5, qq = (in >> 3) & 3, jj = in & 7;
    p[(((t * 4 + c) * 64) + (qq * 16 + mm)) * 8 + jj] = f2bf(ldf(U1, oU + idx, isf32));
  }
  for (int idx = threadIdx.x; idx < 4096; idx += 256) {
    int in = idx >> 6, n = idx & 63;
    int t = n >> 4, mm = n & 15, c = in >> 5, qq = (in >> 3) & 3, jj = in & 7;
    int fi = (((t * 2 + c) * 64) + (qq * 16 + mm)) * 8 + jj;
    p[8192 + fi]  = f2bf(ldf(U2, oW + idx, isf32));
    p[12288 + fi] = f2bf(ldf(W1m, oW + idx, isf32));
    p[16384 + fi] = f2bf(ldf(W2m, oW + idx, isf32));
  }
}

// ---------------- dense-write CSR build (round-13 proven) ----------------

__global__ void k_bcount(const int* __restrict__ dstI, int* __restrict__ bcnt, int E) {
  __shared__ int cl[1024];
  int tid = threadIdx.x;
  for (int t = tid; t < 1024; t += 256) cl[t] = 0;
  __syncthreads();
  for (int i = blockIdx.x * 256 + tid; i < E; i += gridDim.x * 256)
    atomicAdd(&cl[dstI[i] >> 8], 1);
  __syncthreads();
  for (int t = tid; t < 1024; t += 256)
    if (cl[t]) atomicAdd(&bcnt[t], cl[t]);
}

__global__ void k_bscan(const int* __restrict__ bcnt, int* __restrict__ bbase,
                        int* __restrict__ bcur) {
  __shared__ int s[256];
  int tid = threadIdx.x;
  int base = tid * 4;
  int v0 = bcnt[base], v1 = bcnt[base + 1], v2 = bcnt[base + 2], v3 = bcnt[base + 3];
  int tsum = v0 + v1 + v2 + v3;
  s[tid] = tsum;
  __syncthreads();
  for (int off = 1; off < 256; off <<= 1) {
    int x = (tid >= off) ? s[tid - off] : 0;
    __syncthreads();
    s[tid] += x;
    __syncthreads();
  }
  int excl = s[tid] - tsum;
  bbase[base] = excl;           bcur[base] = excl;
  bbase[base + 1] = excl + v0;  bcur[base + 1] = excl + v0;
  bbase[base + 2] = excl + v0 + v1;      bcur[base + 2] = excl + v0 + v1;
  bbase[base + 3] = excl + v0 + v1 + v2; bcur[base + 3] = excl + v0 + v1 + v2;
  if (tid == 255) bbase[1024] = s[255];
}

__global__ void k_bin(const int* __restrict__ srcI, const int* __restrict__ dstI,
                      int* __restrict__ bcur, int2* __restrict__ pairs, int E) {
  __shared__ int cl[1024], cur[1024];
  int tid = threadIdx.x;
  int chunk = (E + gridDim.x - 1) / gridDim.x;
  int s = blockIdx.x * chunk;
  int e = min(s + chunk, E);
  for (int t = tid; t < 1024; t += 256) cl[t] = 0;
  __syncthreads();
  for (int i = s + tid; i < e; i += 256) atomicAdd(&cl[dstI[i] >> 8], 1);
  __syncthreads();
  for (int t = tid; t < 1024; t += 256)
    cur[t] = cl[t] ? atomicAdd(&bcur[t], cl[t]) : 0;
  __syncthreads();
  for (int i = s + tid; i < e; i += 256) {
    int d = dstI[i];
    int p = atomicAdd(&cur[d >> 8], 1);
    pairs[p] = (int2){srcI[i], d};
  }
}

__global__ __launch_bounds__(256) void k_sortb(
    const int2* __restrict__ pairs, const int* __restrict__ bbase,
    int* __restrict__ rowptr, int* __restrict__ srcS, int N, int E, int B) {
  __shared__ int cnt[256], cur[256], s2[256];
  __shared__ int stage[CAP];
  int b = blockIdx.x, tid = threadIdx.x;
  int lo = b << 8;
  int W = min(256, N - lo);
  int s = bbase[b], e = bbase[b + 1];
  cnt[tid] = 0;
  __syncthreads();
  for (int i = s + tid; i < e; i += 256)
    atomicAdd(&cnt[pairs[i].y - lo], 1);
  __syncthreads();
  int v = (tid < W) ? cnt[tid] : 0;
  s2[tid] = v;
  __syncthreads();
  for (int off = 1; off < 256; off <<= 1) {
    int x = (tid >= off) ? s2[tid - off] : 0;
    __syncthreads();
    s2[tid] += x;
    __syncthreads();
  }
  int excl = s2[tid] - v;
  if (tid < W) {
    rowptr[lo + tid] = s + excl;
    cur[tid] = excl;
  }
  if (b == B - 1 && tid == 0) rowptr[N] = E;
  __syncthreads();
  for (int i = s + tid; i < e; i += 256) {
    int2 pr = pairs[i];
    int p = atomicAdd(&cur[pr.y - lo], 1);
    if (p < CAP) stage[p] = pr.x;
    else srcS[s + p] = pr.x;
  }
  __syncthreads();
  int Sb = e - s;
  int lim = Sb < CAP ? Sb : CAP;
  for (int i = tid; i < lim; i += 256) srcS[s + i] = stage[i];
}

// ---------------- dense per-node message MLP (layer 0 only) ----------------
__global__ __launch_bounds__(256) void k_mlp(
    const short* __restrict__ hhi, const short* __restrict__ hlo,
    const void* __restrict__ W1, const void* __restrict__ B1,
    const void* __restrict__ W2, long oW, long oB,
    short* __restrict__ M, const int* __restrict__ flag, int N) {
  __shared__ short w1hi[64 * PADW], w1lo[64 * PADW];
  __shared__ short w2hi[64 * PADW], w2lo[64 * PADW];
  __shared__ float b1s[64];
  __shared__ float tbuf[4][16 * PADT];

  bool isf32 = (*flag != 0);
  int tid = threadIdx.x;
  for (int idx = tid; idx < 4096; idx += 256) {
    int j = idx >> 6, k = idx & 63;
    short hi, lo;
    split2(ldf(W1, oW + idx, isf32), hi, lo);
    w1hi[k * PADW + j] = hi; w1lo[k * PADW + j] = lo;
    split2(ldf(W2, oW + idx, isf32), hi, lo);
    w2hi[k * PADW + j] = hi; w2lo[k * PADW + j] = lo;
  }
  if (tid < 64) b1s[tid] = ldf(B1, oB + tid, isf32);
  __syncthreads();

  const int wave = tid >> 6, lane = tid & 63;
  const int m = lane & 15, quad = lane >> 4;
  float* tb = tbuf[wave];

  for (int nb = blockIdx.x * 64; nb < N; nb += gridDim.x * 64) {
    const int nBase = nb + wave * 16;
    int node = nBase + m;
    int nc = node < N ? node : N - 1;

    short8 fhi[2], flo[2];
    fhi[0] = *(const short8*)(hhi + (long)nc * H + quad * 8);
    fhi[1] = *(const short8*)(hhi + (long)nc * H + 32 + quad * 8);
    flo[0] = *(const short8*)(hlo + (long)nc * H + quad * 8);
    flo[1] = *(const short8*)(hlo + (long)nc * H + 32 + quad * 8);

    floatx4 acc[4];
#pragma unroll
    for (int t = 0; t < 4; ++t) acc[t] = (floatx4){0.f, 0.f, 0.f, 0.f};
#pragma unroll
    for (int t = 0; t < 4; ++t) {
      const short* whi = &w1hi[(t * 16 + m) * PADW + quad * 8];
      const short* wlo = &w1lo[(t * 16 + m) * PADW + quad * 8];
      acc[t] = MFMA(fhi[0], *(const short8*)(whi), acc[t]);
      acc[t] = MFMA(fhi[1], *(const short8*)(whi + 32), acc[t]);
      acc[t] = MFMA(flo[0], *(const short8*)(whi), acc[t]);
      acc[t] = MFMA(flo[1], *(const short8*)(whi + 32), acc[t]);
      acc[t] = MFMA(fhi[0], *(const short8*)(wlo), acc[t]);
      acc[t] = MFMA(fhi[1], *(const short8*)(wlo + 32), acc[t]);
    }

#pragma unroll
    for (int t = 0; t < 4; ++t) {
      int col = t * 16 + m;
      float bb = b1s[col];
#pragma unroll
      for (int r = 0; r < 4; ++r)
        tb[(quad * 4 + r) * PADT + col] = fmaxf(acc[t][r] + bb, 0.f);
    }

    float av[16];
    *(floatx4*)(av + 0)  = *(const floatx4*)(&tb[m * PADT + quad * 8]);
    *(floatx4*)(av + 4)  = *(const floatx4*)(&tb[m * PADT + quad * 8 + 4]);
    *(floatx4*)(av + 8)  = *(const floatx4*)(&tb[m * PADT + 32 + quad * 8]);
    *(floatx4*)(av + 12) = *(const floatx4*)(&tb[m * PADT + 32 + quad * 8 + 4]);
    short8 thi0, tlo0, thi1, tlo1;
#pragma unroll
    for (int j = 0; j < 8; ++j) {
      short hi, lo;
      split2(av[j], hi, lo);     thi0[j] = hi; tlo0[j] = lo;
      split2(av[8 + j], hi, lo); thi1[j] = hi; tlo1[j] = lo;
    }

    floatx4 mac[4];
#pragma unroll
    for (int t = 0; t < 4; ++t) mac[t] = (floatx4){0.f, 0.f, 0.f, 0.f};
#pragma unroll
    for (int t = 0; t < 4; ++t) {
      const short* whi = &w2hi[(t * 16 + m) * PADW + quad * 8];
      const short* wlo = &w2lo[(t * 16 + m) * PADW + quad * 8];
      mac[t] = MFMA(thi0, *(const short8*)(whi), mac[t]);
      mac[t] = MFMA(thi1, *(const short8*)(whi + 32), mac[t]);
      mac[t] = MFMA(tlo0, *(const short8*)(whi), mac[t]);
      mac[t] = MFMA(tlo1, *(const short8*)(whi + 32), mac[t]);
      mac[t] = MFMA(thi0, *(const short8*)(wlo), mac[t]);
      mac[t] = MFMA(thi1, *(const short8*)(wlo + 32), mac[t]);
    }

#pragma unroll
    for (int t = 0; t < 4; ++t) {
      int col = t * 16 + m;
#pragma unroll
      for (int r = 0; r < 4; ++r) {
        int nrow = nBase + quad * 4 + r;
        if (nrow < N) M[(long)nrow * H + col] = f2bf(mac[t][r]);
      }
    }
  }
}

// ---------------- gather-sum: agg[d] = sum_seg M[src] + deg*b2 ----------------
__global__ __launch_bounds__(256) void k_gather(
    const short* __restrict__ M, const int* __restrict__ rowptr,
    const int* __restrict__ srcS, const void* __restrict__ B2, long oB,
    short* __restrict__ agg, const int* __restrict__ flag, int N, int totWaves) {
  __shared__ float b2s[64];
  bool isf32 = (*flag != 0);
  if (threadIdx.x < 64) b2s[threadIdx.x] = ldf(B2, oB + threadIdx.x, isf32);
  __syncthreads();
  const int wave = threadIdx.x >> 6, lane = threadIdx.x & 63;
  const int g = lane >> 4, l = lane & 15;
  float b2v[4];
#pragma unroll
  for (int j = 0; j < 4; ++j) b2v[j] = b2s[l * 4 + j];

  const int gw = blockIdx.x * 4 + wave;
  const int nTask = (N + 3) >> 2;
  for (int task = gw; task < nTask; task += totWaves) {
    int n = task * 4 + g;
    bool valid = n < N;
    int nc = valid ? n : N - 1;
    int rs = rowptr[nc], re = rowptr[nc + 1];
    if (!valid) { rs = 0; re = 0; }
    float a0 = 0.f, a1 = 0.f, a2 = 0.f, a3 = 0.f;
    for (int e = rs; e < re; e += 8) {
      int sv[8];
#pragma unroll
      for (int u = 0; u < 8; ++u) {
        int c = e + u < re ? e + u : re - 1;
        sv[u] = srcS[c];
      }
      short4v rr[8];
#pragma unroll
      for (int u = 0; u < 8; ++u)
        rr[u] = *(const short4v*)(M + (long)sv[u] * H + l * 4);
#pragma unroll
      for (int u = 0; u < 8; ++u) {
        if (e + u < re) {
          a0 += bf2f(rr[u][0]); a1 += bf2f(rr[u][1]);
          a2 += bf2f(rr[u][2]); a3 += bf2f(rr[u][3]);
        }
      }
    }
    if (valid) {
      float dv = (float)(re - rs);
      short4v o;
      o[0] = f2bf(a0 + dv * b2v[0]);
      o[1] = f2bf(a1 + dv * b2v[1]);
      o[2] = f2bf(a2 + dv * b2v[2]);
      o[3] = f2bf(a3 + dv * b2v[3]);
      *(short4v*)(agg + (long)n * H + l * 4) = o;
    }
  }
}

// ---------------- persistent fused update + next-layer message MLP ----------------
// Weights from prepped frag-major bank: staging = vector copy; m2 loads direct
// from global to registers (no LDS pass, single barrier). LDS ~50.3KB -> 3/CU.
__global__ __launch_bounds__(256) void k_updm(
    short* __restrict__ hhi, short* __restrict__ hlo, const short* __restrict__ agg,
    const short* __restrict__ pw, const short* __restrict__ pwn,
    const void* __restrict__ UB1, const void* __restrict__ UB2,
    const void* __restrict__ G, const void* __restrict__ Bb,
    const void* __restrict__ Mm, const void* __restrict__ Vv,
    const void* __restrict__ B1m,
    long oB, long oBn,
    short* __restrict__ Mout, const int* __restrict__ flag, int N, int doMsg) {
  __shared__ short u1f[8192];
  __shared__ short u2f[4096];
  __shared__ short m1f[4096];
  __shared__ float b1s[64], b2s[64], scl[64], sft[64], mb1[64];
  __shared__ float tbuf[4][16 * PADT];

  bool isf32 = (*flag != 0);
  int tid = threadIdx.x;
  const int wave = tid >> 6, lane = tid & 63;
  const int m = lane & 15, quad = lane >> 4;

  // staging: pure vector copies from the prepped bank
  for (int c = tid; c < 1024; c += 256)
    ((short8*)u1f)[c] = ((const short8*)pw)[c];
  for (int c = tid; c < 512; c += 256) {
    ((short8*)u2f)[c] = ((const short8*)(pw + 8192))[c];
    ((short8*)m1f)[c] = ((const short8*)(pwn + 12288))[c];
  }
  // m2: direct global->register fragment loads (coalesced 16B/lane)
  short8 m2r[4][2];
#pragma unroll
  for (int t = 0; t < 4; ++t)
#pragma unroll
    for (int c = 0; c < 2; ++c)
      m2r[t][c] = *(const short8*)&pwn[16384 + (((t * 2 + c) * 64) + lane) * 8];
  if (tid < 64) {
    b1s[tid] = ldf(UB1, oB + tid, isf32);
    b2s[tid] = ldf(UB2, oB + tid, isf32);
    float s = ldf(G, oB + tid, isf32) * rsqrtf(ldf(Vv, oB + tid, isf32) + 1e-5f);
    scl[tid] = s;
    sft[tid] = ldf(Bb, oB + tid, isf32) - ldf(Mm, oB + tid, isf32) * s;
    mb1[tid] = ldf(B1m, oBn + tid, isf32);
  }
  __syncthreads();

  float* tb = tbuf[wave];

  for (int nb = blockIdx.x * 64; nb < N; nb += gridDim.x * 64) {
    const int nBase = nb + wave * 16;
    int node = nBase + m;
    int nc = node < N ? node : N - 1;

    short8 fhi[4], flo[2];
    fhi[0] = *(const short8*)(hhi + (long)nc * H + quad * 8);
    fhi[1] = *(const short8*)(hhi + (long)nc * H + 32 + quad * 8);
    flo[0] = *(const short8*)(hlo + (long)nc * H + quad * 8);
    flo[1] = *(const short8*)(hlo + (long)nc * H + 32 + quad * 8);
    fhi[2] = *(const short8*)(agg + (long)nc * H + quad * 8);
    fhi[3] = *(const short8*)(agg + (long)nc * H + 32 + quad * 8);

    floatx4 acc[4];
#pragma unroll
    for (int t = 0; t < 4; ++t) acc[t] = (floatx4){0.f, 0.f, 0.f, 0.f};
#pragma unroll
    for (int t = 0; t < 4; ++t) {
#pragma unroll
      for (int c = 0; c < 4; ++c) {
        const short8 w = *(const short8*)&u1f[(((t * 4 + c) * 64) + lane) * 8];
        acc[t] = MFMA(fhi[c], w, acc[t]);
        if (c < 2) acc[t] = MFMA(flo[c], w, acc[t]);
      }
    }

#pragma unroll
    for (int t = 0; t < 4; ++t) {
      int col = t * 16 + m;
      float bb = b1s[col];
#pragma unroll
      for (int r = 0; r < 4; ++r)
        tb[(quad * 4 + r) * PADT + col] = fmaxf(acc[t][r] + bb, 0.f);
    }
    float av[16];
    *(floatx4*)(av + 0)  = *(const floatx4*)(&tb[m * PADT + quad * 8]);
    *(floatx4*)(av + 4)  = *(const floatx4*)(&tb[m * PADT + quad * 8 + 4]);
    *(floatx4*)(av + 8)  = *(const floatx4*)(&tb[m * PADT + 32 + quad * 8]);
    *(floatx4*)(av + 12) = *(const floatx4*)(&tb[m * PADT + 32 + quad * 8 + 4]);
    short8 thi[2], tlo[2];
#pragma unroll
    for (int j = 0; j < 8; ++j) {
      short hi, lo;
      split2(av[j], hi, lo);     thi[0][j] = hi; tlo[0][j] = lo;
      split2(av[8 + j], hi, lo); thi[1][j] = hi; tlo[1][j] = lo;
    }

    floatx4 mac[4];
#pragma unroll
    for (int t = 0; t < 4; ++t) mac[t] = (floatx4){0.f, 0.f, 0.f, 0.f};
#pragma unroll
    for (int t = 0; t < 4; ++t) {
#pragma unroll
      for (int c = 0; c < 2; ++c) {
        const short8 w = *(const short8*)&u2f[(((t * 2 + c) * 64) + lane) * 8];
        mac[t] = MFMA(thi[c], w, mac[t]);
        mac[t] = MFMA(tlo[c], w, mac[t]);
      }
    }

#pragma unroll
    for (int t = 0; t < 4; ++t) {
      int col = t * 16 + m;
      float bb = b2s[col], ss = scl[col], ff = sft[col];
#pragma unroll
      for (int r = 0; r < 4; ++r) {
        int nrow = nBase + quad * 4 + r;
        float hn = 0.f;
        if (nrow < N) {
          long el = (long)nrow * H + col;
          float hv = (mac[t][r] + bb) * ss + ff;
          float ho = bf2f(hhi[el]) + bf2f(hlo[el]);
          hn = fmaxf(hv + ho, 0.f);
          short hi2, lo2; split2(hn, hi2, lo2);
          hhi[el] = hi2; hlo[el] = lo2;
        }
        tb[(quad * 4 + r) * PADT + col] = hn;
      }
    }

    if (doMsg) {
      *(floatx4*)(av + 0)  = *(const floatx4*)(&tb[m * PADT + quad * 8]);
      *(floatx4*)(av + 4)  = *(const floatx4*)(&tb[m * PADT + quad * 8 + 4]);
      *(floatx4*)(av + 8)  = *(const floatx4*)(&tb[m * PADT + 32 + quad * 8]);
      *(floatx4*)(av + 12) = *(const floatx4*)(&tb[m * PADT + 32 + quad * 8 + 4]);
#pragma unroll
      for (int j = 0; j < 8; ++j) {
        short hi, lo;
        split2(av[j], hi, lo);     thi[0][j] = hi; tlo[0][j] = lo;
        split2(av[8 + j], hi, lo); thi[1][j] = hi; tlo[1][j] = lo;
      }

#pragma unroll
      for (int t = 0; t < 4; ++t) acc[t] = (floatx4){0.f, 0.f, 0.f, 0.f};
#pragma unroll
      for (int t = 0; t < 4; ++t) {
#pragma unroll
        for (int c = 0; c < 2; ++c) {
          const short8 w = *(const short8*)&m1f[(((t * 2 + c) * 64) + lane) * 8];
          acc[t] = MFMA(thi[c], w, acc[t]);
          acc[t] = MFMA(tlo[c], w, acc[t]);
        }
      }

#pragma unroll
      for (int t = 0; t < 4; ++t) {
        int col = t * 16 + m;
        float bb = mb1[col];
#pragma unroll
        for (int r = 0; r < 4; ++r)
          tb[(quad * 4 + r) * PADT + col] = fmaxf(acc[t][r] + bb, 0.f);
      }
      *(floatx4*)(av + 0)  = *(const floatx4*)(&tb[m * PADT + quad * 8]);
      *(floatx4*)(av + 4)  = *(const floatx4*)(&tb[m * PADT + quad * 8 + 4]);
      *(floatx4*)(av + 8)  = *(const floatx4*)(&tb[m * PADT + 32 + quad * 8]);
      *(floatx4*)(av + 12) = *(const floatx4*)(&tb[m * PADT + 32 + quad * 8 + 4]);
#pragma unroll
      for (int j = 0; j < 8; ++j) {
        short hi, lo;
        split2(av[j], hi, lo);     thi[0][j] = hi; tlo[0][j] = lo;
        split2(av[8 + j], hi, lo); thi[1][j] = hi; tlo[1][j] = lo;
      }

#pragma unroll
      for (int t = 0; t < 4; ++t) mac[t] = (floatx4){0.f, 0.f, 0.f, 0.f};
#pragma unroll
      for (int t = 0; t < 4; ++t) {
#pragma unroll
        for (int c = 0; c < 2; ++c) {
          mac[t] = MFMA(thi[c], m2r[t][c], mac[t]);
          mac[t] = MFMA(tlo[c], m2r[t][c], mac[t]);
        }
      }

#pragma unroll
      for (int t = 0; t < 4; ++t) {
        int col = t * 16 + m;
#pragma unroll
        for (int r = 0; r < 4; ++r) {
          int nrow = nBase + quad * 4 + r;
          if (nrow < N) Mout[(long)nrow * H + col] = f2bf(mac[t][r]);
        }
      }
    }
  }
}

// readout from hi/lo planes
__global__ __launch_bounds__(256) void k_out2(
    const short* __restrict__ hhi, const short* __restrict__ hlo,
    const void* __restrict__ W1, const void* __restrict__ B1,
    const void* __restrict__ W2, const void* __restrict__ B2,
    void* __restrict__ out, const int* __restrict__ flag, int NQ) {
  __shared__ float w1s[64 * 32];
  __shared__ float b1sh[32], w2s[32];
  bool isf32 = (*flag != 0);
  int tid = threadIdx.x;
  for (int idx = tid; idx < 2048; idx += 256) w1s[idx] = ldf(W1, idx, isf32);
  if (tid < 32) { b1sh[tid] = ldf(B1, tid, isf32); w2s[tid] = ldf(W2, tid, isf32); }
  __syncthreads();
  int v = blockIdx.x * 256 + tid;
  if (v >= NQ) return;
  float hr[64];
#pragma unroll
  for (int j = 0; j < 64; ++j)
    hr[j] = bf2f(hhi[(long)v * H + j]) + bf2f(hlo[(long)v * H + j]);
  float accum = ldf(B2, 0, isf32);
#pragma unroll 4
  for (int k = 0; k < 32; ++k) {
    float t = b1sh[k];
#pragma unroll
    for (int j = 0; j < 64; ++j) t += hr[j] * w1s[j * 32 + k];
    accum += fmaxf(t, 0.f) * w2s[k];
  }
  if (isf32) ((float*)out)[v] = accum;
  else ((short*)out)[v] = f2bf(accum);
}

extern "C" void kernel_launch(void* const* d_in, const int* in_sizes, int n_in,
                              void* d_out, int out_size, void* d_ws, size_t ws_size,
                              hipStream_t stream) {
  const void* x      = d_in[0];
  const int*  ei     = (const int*)d_in[1];
  const void* w_in   = d_in[3];
  const void* b_in   = d_in[4];
  const void* msg_w1 = d_in[5];
  const void* msg_b1 = d_in[6];
  const void* msg_w2 = d_in[7];
  const void* msg_b2 = d_in[8];
  const void* upd_w1 = d_in[9];
  const void* upd_b1 = d_in[10];
  const void* upd_w2 = d_in[11];
  const void* upd_b2 = d_in[12];
  const void* bn_g   = d_in[13];
  const void* bn_b   = d_in[14];
  const void* bn_m   = d_in[15];
  const void* bn_v   = d_in[16];
  const void* out_w1 = d_in[17];
  const void* out_b1 = d_in[18];
  const void* out_w2 = d_in[19];
  const void* out_b2 = d_in[20];

  const int N = in_sizes[0] / 3;
  const int E = in_sizes[1] / 2;
  const int L = in_sizes[5] / (H * H);
  const int* srcI = ei;
  const int* dstI = ei + E;
  const int B = (N + 255) >> 8;

  // workspace layout (256B-aligned slots)
  size_t off = 0;
  auto alloc = [&](size_t bytes) { size_t o = off; off += (bytes + 255) & ~(size_t)255; return o; };
  size_t mSize = (size_t)N * H * sizeof(short);
  size_t pSize = (size_t)E * sizeof(int2);
  size_t o_flag   = alloc(256);
  size_t o_bcnt   = alloc(1024 * sizeof(int));
  size_t o_bbase  = alloc(1025 * sizeof(int));
  size_t o_bcur   = alloc(1024 * sizeof(int));
  size_t o_prep   = alloc((size_t)L * WSTRIDE * sizeof(short));
  size_t o_hhi    = alloc((size_t)N * H * sizeof(short));
  size_t o_hlo    = alloc((size_t)N * H * sizeof(short));
  size_t o_agg    = alloc((size_t)N * H * sizeof(short));
  size_t o_M      = alloc(mSize > pSize ? mSize : pSize);  // M overlays pairs
  size_t o_rowptr = alloc((size_t)(N + 1) * sizeof(int));
  size_t o_srcS   = alloc((size_t)E * sizeof(int));

  char* ws = (char*)d_ws;
  int*   flag   = (int*)(ws + o_flag);
  int*   bcnt   = (int*)(ws + o_bcnt);
  int*   bbase  = (int*)(ws + o_bbase);
  int*   bcur   = (int*)(ws + o_bcur);
  short* prep   = (short*)(ws + o_prep);
  short* hhi    = (short*)(ws + o_hhi);
  short* hlo    = (short*)(ws + o_hlo);
  short* aggS   = (short*)(ws + o_agg);
  short* Mbuf   = (short*)(ws + o_M);
  int2*  pairs  = (int2*)(ws + o_M);
  int*   rowptr = (int*)(ws + o_rowptr);
  int*   srcS   = (int*)(ws + o_srcS);

  k_probe<<<1, 256, 0, stream>>>((const short*)x, flag);
  k_prep<<<L, 256, 0, stream>>>(upd_w1, upd_w2, msg_w1, msg_w2, prep, flag);
  k_input2<<<(N * H + 255) / 256, 256, 0, stream>>>(x, w_in, b_in, hhi, hlo, flag, N);

  // dense-write CSR build
  hipMemsetAsync(bcnt, 0, 1024 * sizeof(int), stream);
  k_bcount<<<256, 256, 0, stream>>>(dstI, bcnt, E);
  k_bscan<<<1, 256, 0, stream>>>(bcnt, bbase, bcur);
  k_bin<<<256, 256, 0, stream>>>(srcI, dstI, bcur, pairs, E);
  k_sortb<<<B, 256, 0, stream>>>(pairs, bbase, rowptr, srcS, N, E, B);

  // M_0 (full-precision standalone MLP, persistent) — after pairs is dead
  k_mlp<<<768, 256, 0, stream>>>(hhi, hlo,
      msg_w1, msg_b1, msg_w2, 0, 0, Mbuf, flag, N);

  const int GB = 2048;
  const int UB = 768;  // persistent k_updm: 3 blocks/CU (LDS ~50.3KB)
  for (int i = 0; i < L; ++i) {
    long oB = (long)i * H;
    int doMsg = (i + 1 < L) ? 1 : 0;
    int iN = doMsg ? i + 1 : i;  // clamped (m1/m2 unused when !doMsg)
    long oBn = doMsg ? (long)(i + 1) * H : 0;
    k_gather<<<GB, 256, 0, stream>>>(Mbuf, rowptr, srcS,
        msg_b2, oB, aggS, flag, N, GB * 4);
    k_updm<<<UB, 256, 0, stream>>>(hhi, hlo, aggS,
        prep + (size_t)i * WSTRIDE, prep + (size_t)iN * WSTRIDE,
        upd_b1, upd_b2, bn_g, bn_b, bn_m, bn_v, msg_b1,
        oB, oBn, Mbuf, flag, N, doMsg);
  }
  k_out2<<<(out_size + 255) / 256, 256, 0, stream>>>(hhi, hlo,
      out_w1, out_b1, out_w2, out_b2, d_out, flag, out_size);
}